// Round 1
// baseline (11614.639 us; speedup 1.0000x reference)
//
#include <hip/hip_runtime.h>
#include <hip/hip_bf16.h>
#include <math.h>

// GPT forward, fp32 baseline.
// V=32000 L=6 H=16 D=1024 S=512 B=4, DK=64, DF=4096.
#define V_SIZE 32000
#define L_NUM 6
#define H_NUM 16
#define D_MODEL 1024
#define S_LEN 512
#define B_SZ 4
#define DF_DIM 4096
#define ROWS (B_SZ * S_LEN)   // 2048

// ---------------- embedding + sinusoidal PE ----------------
__global__ __launch_bounds__(256) void embed_kernel(
    const int* __restrict__ x, const float* __restrict__ tok_emb,
    float* __restrict__ h) {
  int row = blockIdx.x;            // 0..ROWS-1
  int s = row % S_LEN;
  int tok = x[row];
  const float* te = tok_emb + (size_t)tok * D_MODEL;
  float* hr = h + (size_t)row * D_MODEL;
  float pos = (float)s;
  const float c = 9.210340371976184f / (float)D_MODEL;  // ln(10000)/D
#pragma unroll
  for (int i = 0; i < D_MODEL / 256; ++i) {
    int d = threadIdx.x + i * 256;
    float freq = expf(-(float)(d & ~1) * c);
    float ang = pos * freq;
    float pe = (d & 1) ? cosf(ang) : sinf(ang);
    hr[d] = te[d] + pe;
  }
}

// ---------------- layernorm (one block per row) ----------------
__global__ __launch_bounds__(256) void layernorm_kernel(
    const float* __restrict__ in, const float* __restrict__ g,
    const float* __restrict__ b, float* __restrict__ out) {
  int row = blockIdx.x;
  const float* xr = in + (size_t)row * D_MODEL;
  float vals[D_MODEL / 256];
  float s1 = 0.f, s2 = 0.f;
#pragma unroll
  for (int i = 0; i < D_MODEL / 256; ++i) {
    int d = threadIdx.x + i * 256;
    float v = xr[d];
    vals[i] = v;
    s1 += v;
    s2 += v * v;
  }
#pragma unroll
  for (int off = 32; off; off >>= 1) {
    s1 += __shfl_xor(s1, off, 64);
    s2 += __shfl_xor(s2, off, 64);
  }
  __shared__ float w1s[4], w2s[4];
  int wid = threadIdx.x >> 6;
  if ((threadIdx.x & 63) == 0) { w1s[wid] = s1; w2s[wid] = s2; }
  __syncthreads();
  s1 = w1s[0] + w1s[1] + w1s[2] + w1s[3];
  s2 = w2s[0] + w2s[1] + w2s[2] + w2s[3];
  float mu = s1 * (1.0f / D_MODEL);
  float var = s2 * (1.0f / D_MODEL) - mu * mu;
  float rstd = rsqrtf(var + 1e-5f);
  float* orow = out + (size_t)row * D_MODEL;
#pragma unroll
  for (int i = 0; i < D_MODEL / 256; ++i) {
    int d = threadIdx.x + i * 256;
    orow[d] = (vals[i] - mu) * rstd * g[d] + b[d];
  }
}

// ---------------- fp32 tiled GEMM: C[M,N] = A[M,K] @ W[K,N] (+bias)(+gelu)(+residual) ----------------
// BM=BN=64, BK=16, 256 threads, 4x4 micro-tile per thread.
// M,N multiples of 64; K multiple of 16 (true for all shapes here).
template <bool GELU_ACT, bool RES>
__global__ __launch_bounds__(256) void gemm_kernel(
    const float* __restrict__ A, const float* __restrict__ W,
    const float* __restrict__ bias, const float* __restrict__ R,
    float* __restrict__ C, int M, int N, int K) {
  __shared__ float As[16][65];   // [k][row], padded
  __shared__ float Bs[16][64];   // [k][col]
  int tid = threadIdx.x;
  int tx = tid & 15, ty = tid >> 4;
  int bm = blockIdx.y, bn = blockIdx.x;
  const float* Ablk = A + (size_t)bm * 64 * K;
  const float* Wblk = W + (size_t)bn * 64;
  float acc[4][4] = {};
  for (int k0 = 0; k0 < K; k0 += 16) {
#pragma unroll
    for (int i = 0; i < 4; ++i) {
      int e = tid + i * 256;
      int r = e >> 4, c = e & 15;
      As[c][r] = Ablk[(size_t)r * K + k0 + c];
    }
#pragma unroll
    for (int i = 0; i < 4; ++i) {
      int e = tid + i * 256;
      int r = e >> 6, c = e & 63;
      Bs[r][c] = Wblk[(size_t)(k0 + r) * N + c];
    }
    __syncthreads();
#pragma unroll
    for (int kk = 0; kk < 16; ++kk) {
      float a[4], bv[4];
#pragma unroll
      for (int i = 0; i < 4; ++i) a[i] = As[kk][ty * 4 + i];
#pragma unroll
      for (int j = 0; j < 4; ++j) bv[j] = Bs[kk][tx * 4 + j];
#pragma unroll
      for (int i = 0; i < 4; ++i)
#pragma unroll
        for (int j = 0; j < 4; ++j) acc[i][j] += a[i] * bv[j];
    }
    __syncthreads();
  }
#pragma unroll
  for (int i = 0; i < 4; ++i) {
    int row = bm * 64 + ty * 4 + i;
    int col = bn * 64 + tx * 4;
    float o[4];
#pragma unroll
    for (int j = 0; j < 4; ++j) {
      o[j] = acc[i][j];
      if (bias) o[j] += bias[col + j];
      if (GELU_ACT) o[j] = 0.5f * o[j] * (1.0f + erff(o[j] * 0.70710678118f));
      if (RES) o[j] += R[(size_t)row * N + col + j];
    }
    *(float4*)&C[(size_t)row * N + col] = make_float4(o[0], o[1], o[2], o[3]);
  }
}

// ---------------- fused causal attention: one wave per (b,h,qpos) ----------------
__global__ __launch_bounds__(64) void attn_kernel(
    const float* __restrict__ q, const float* __restrict__ k,
    const float* __restrict__ v, float* __restrict__ ctx) {
  int qpos = blockIdx.x;
  int bh = blockIdx.y;
  int b = bh >> 4;   // / H_NUM
  int h = bh & 15;   // % H_NUM
  int lane = threadIdx.x;
  __shared__ float qs[64];
  __shared__ float sc[S_LEN];
  __shared__ float Ks[64][65];
  const size_t base = (size_t)b * S_LEN * D_MODEL + (size_t)h * 64;
  qs[lane] = q[base + (size_t)qpos * D_MODEL + lane];
#pragma unroll
  for (int i = 0; i < S_LEN / 64; ++i) sc[lane + i * 64] = -1e9f;
  __syncthreads();
  const float scale = 0.125f;  // 1/sqrt(64)
  int ntile = (qpos >> 6) + 1;
  for (int t = 0; t < ntile; ++t) {
    int k0 = t * 64;
#pragma unroll 8
    for (int j = 0; j < 64; ++j)
      Ks[j][lane] = k[base + (size_t)(k0 + j) * D_MODEL + lane];
    __syncthreads();
    int kk = k0 + lane;
    if (kk <= qpos) {
      float s = 0.f;
#pragma unroll
      for (int d = 0; d < 64; ++d) s += qs[d] * Ks[lane][d];
      sc[kk] = s * scale;
    }
    __syncthreads();
  }
  float m = -1e30f;
#pragma unroll
  for (int i = 0; i < S_LEN / 64; ++i) m = fmaxf(m, sc[lane + i * 64]);
#pragma unroll
  for (int off = 32; off; off >>= 1) m = fmaxf(m, __shfl_xor(m, off, 64));
  float sum = 0.f;
#pragma unroll
  for (int i = 0; i < S_LEN / 64; ++i) {
    float e = expf(sc[lane + i * 64] - m);
    sc[lane + i * 64] = e;
    sum += e;
  }
#pragma unroll
  for (int off = 32; off; off >>= 1) sum += __shfl_xor(sum, off, 64);
  __syncthreads();
  float inv = 1.f / sum;
  float acc = 0.f;
  int kmax = qpos + 1;
  for (int kk2 = 0; kk2 < kmax; ++kk2)
    acc += sc[kk2] * v[base + (size_t)kk2 * D_MODEL + lane];
  ctx[base + (size_t)qpos * D_MODEL + lane] = acc * inv;
}

// ---------------- launch ----------------
extern "C" void kernel_launch(void* const* d_in, const int* in_sizes, int n_in,
                              void* d_out, int out_size, void* d_ws, size_t ws_size,
                              hipStream_t stream) {
  const int* x = (const int*)d_in[0];
  const float* tok_emb = (const float*)d_in[1];
  const float* wq = (const float*)d_in[2];
  const float* bq = (const float*)d_in[3];
  const float* wk = (const float*)d_in[4];
  const float* bk = (const float*)d_in[5];
  const float* wv = (const float*)d_in[6];
  const float* bv = (const float*)d_in[7];
  const float* wo = (const float*)d_in[8];
  const float* bo = (const float*)d_in[9];
  const float* ln1_g = (const float*)d_in[10];
  const float* ln1_b = (const float*)d_in[11];
  const float* w1 = (const float*)d_in[12];
  const float* b1 = (const float*)d_in[13];
  const float* w2 = (const float*)d_in[14];
  const float* b2 = (const float*)d_in[15];
  const float* ln2_g = (const float*)d_in[16];
  const float* ln2_b = (const float*)d_in[17];
  const float* lnf_g = (const float*)d_in[18];
  const float* lnf_b = (const float*)d_in[19];
  const float* lm_w = (const float*)d_in[20];

  float* ws = (float*)d_ws;
  const size_t BSD = (size_t)ROWS * D_MODEL;  // 2 Mi elements
  float* h  = ws;                // residual stream
  float* hn = ws + 1 * BSD;      // layernorm out
  float* qb = ws + 2 * BSD;
  float* kb = ws + 3 * BSD;
  float* vb = ws + 4 * BSD;
  float* cb = ws + 5 * BSD;
  float* ff = ws + 2 * BSD;      // aliases q/k/v/ctx region (free after attn out-proj); 4*BSD

  embed_kernel<<<ROWS, 256, 0, stream>>>(x, tok_emb, h);

  dim3 gD(D_MODEL / 64, ROWS / 64);
  dim3 gF(DF_DIM / 64, ROWS / 64);
  dim3 gV(V_SIZE / 64, ROWS / 64);
  for (int l = 0; l < L_NUM; ++l) {
    size_t woff = (size_t)l * D_MODEL * D_MODEL;
    layernorm_kernel<<<ROWS, 256, 0, stream>>>(h, ln1_g + l * D_MODEL, ln1_b + l * D_MODEL, hn);
    gemm_kernel<false, false><<<gD, 256, 0, stream>>>(hn, wq + woff, bq + l * D_MODEL, nullptr, qb, ROWS, D_MODEL, D_MODEL);
    gemm_kernel<false, false><<<gD, 256, 0, stream>>>(hn, wk + woff, bk + l * D_MODEL, nullptr, kb, ROWS, D_MODEL, D_MODEL);
    gemm_kernel<false, false><<<gD, 256, 0, stream>>>(hn, wv + woff, bv + l * D_MODEL, nullptr, vb, ROWS, D_MODEL, D_MODEL);
    attn_kernel<<<dim3(S_LEN, B_SZ * H_NUM), 64, 0, stream>>>(qb, kb, vb, cb);
    gemm_kernel<false, true><<<gD, 256, 0, stream>>>(cb, wo + woff, bo + l * D_MODEL, h, h, ROWS, D_MODEL, D_MODEL);
    layernorm_kernel<<<ROWS, 256, 0, stream>>>(h, ln2_g + l * D_MODEL, ln2_b + l * D_MODEL, hn);
    gemm_kernel<true, false><<<gF, 256, 0, stream>>>(hn, w1 + (size_t)l * D_MODEL * DF_DIM, b1 + l * DF_DIM, nullptr, ff, ROWS, DF_DIM, D_MODEL);
    gemm_kernel<false, true><<<gD, 256, 0, stream>>>(ff, w2 + (size_t)l * DF_DIM * D_MODEL, b2 + l * D_MODEL, h, h, ROWS, D_MODEL, DF_DIM);
  }
  layernorm_kernel<<<ROWS, 256, 0, stream>>>(h, lnf_g, lnf_b, hn);
  gemm_kernel<false, false><<<gV, 256, 0, stream>>>(hn, lm_w, nullptr, nullptr, (float*)d_out, ROWS, V_SIZE, D_MODEL);
}

// Round 2
// 4655.994 us; speedup vs baseline: 2.4946x; 2.4946x over previous
//
#include <hip/hip_runtime.h>
#include <hip/hip_bf16.h>
#include <math.h>

// GPT forward. V=32000 L=6 H=16 D=1024 S=512 B=4, DK=64, DF=4096.
// Round 1: bf16 MFMA GEMMs (m97 structure: 128x128 tile, global_load_lds,
// 16x16x32 bf16 MFMA), weights pre-transposed to [N][K] bf16 in ws.
#define V_SIZE 32000
#define L_NUM 6
#define H_NUM 16
#define D_MODEL 1024
#define S_LEN 512
#define B_SZ 4
#define DF_DIM 4096
#define ROWS (B_SZ * S_LEN)   // 2048
#define QKV_N (3 * D_MODEL)   // 3072

typedef unsigned short u16;
typedef __attribute__((ext_vector_type(8))) short short8v;   // 8 bf16
typedef __attribute__((ext_vector_type(4))) float f32x4;

__device__ __forceinline__ float b2f(u16 b) {
  union { float f; unsigned u; } c; c.u = ((unsigned)b) << 16; return c.f;
}
__device__ __forceinline__ u16 f2b(float f) {
  __hip_bfloat16 h = __float2bfloat16(f);
  union { __hip_bfloat16 h; u16 u; } c; c.h = h; return c.u;
}
__device__ __forceinline__ void g2l16(const void* g, void* l) {
  __builtin_amdgcn_global_load_lds(
      (const __attribute__((address_space(1))) void*)g,
      (__attribute__((address_space(3))) void*)l, 16, 0, 0);
}

// ---------------- embedding + sinusoidal PE (fp32 out) ----------------
__global__ __launch_bounds__(256) void embed_kernel(
    const int* __restrict__ x, const float* __restrict__ tok_emb,
    float* __restrict__ h) {
  int row = blockIdx.x;
  int s = row % S_LEN;
  int tok = x[row];
  const float* te = tok_emb + (size_t)tok * D_MODEL;
  float* hr = h + (size_t)row * D_MODEL;
  float pos = (float)s;
  const float c = 9.210340371976184f / (float)D_MODEL;  // ln(10000)/D
#pragma unroll
  for (int i = 0; i < D_MODEL / 256; ++i) {
    int d = threadIdx.x + i * 256;
    float freq = expf(-(float)(d & ~1) * c);
    float ang = pos * freq;
    float pe = (d & 1) ? cosf(ang) : sinf(ang);
    hr[d] = te[d] + pe;
  }
}

// ---------------- layernorm: fp32 in -> bf16 out ----------------
__global__ __launch_bounds__(256) void layernorm_kernel(
    const float* __restrict__ in, const float* __restrict__ g,
    const float* __restrict__ b, u16* __restrict__ out) {
  int row = blockIdx.x;
  const float* xr = in + (size_t)row * D_MODEL;
  float vals[D_MODEL / 256];
  float s1 = 0.f, s2 = 0.f;
#pragma unroll
  for (int i = 0; i < D_MODEL / 256; ++i) {
    int d = threadIdx.x + i * 256;
    float v = xr[d];
    vals[i] = v;
    s1 += v;
    s2 += v * v;
  }
#pragma unroll
  for (int off = 32; off; off >>= 1) {
    s1 += __shfl_xor(s1, off, 64);
    s2 += __shfl_xor(s2, off, 64);
  }
  __shared__ float w1s[4], w2s[4];
  int wid = threadIdx.x >> 6;
  if ((threadIdx.x & 63) == 0) { w1s[wid] = s1; w2s[wid] = s2; }
  __syncthreads();
  s1 = w1s[0] + w1s[1] + w1s[2] + w1s[3];
  s2 = w2s[0] + w2s[1] + w2s[2] + w2s[3];
  float mu = s1 * (1.0f / D_MODEL);
  float var = s2 * (1.0f / D_MODEL) - mu * mu;
  float rstd = rsqrtf(var + 1e-5f);
  u16* orow = out + (size_t)row * D_MODEL;
#pragma unroll
  for (int i = 0; i < D_MODEL / 256; ++i) {
    int d = threadIdx.x + i * 256;
    orow[d] = f2b((vals[i] - mu) * rstd * g[d] + b[d]);
  }
}

// ---------------- fp32 [K][N] -> bf16 [N][K] transpose ----------------
__global__ __launch_bounds__(256) void transpose_cvt(
    const float* __restrict__ W, u16* __restrict__ Wt, int K, int N) {
  __shared__ float t[32][33];
  const int n0 = blockIdx.x * 32, k0 = blockIdx.y * 32;
  const int tx = threadIdx.x & 31, ty = threadIdx.x >> 5;
#pragma unroll
  for (int i = 0; i < 32; i += 8)
    t[ty + i][tx] = W[(size_t)(k0 + ty + i) * N + n0 + tx];
  __syncthreads();
#pragma unroll
  for (int i = 0; i < 32; i += 8)
    Wt[(size_t)(n0 + ty + i) * K + k0 + tx] = f2b(t[tx][ty + i]);
}

// ---------------- pack bq|bk|bv -> [L][3072] ----------------
__global__ __launch_bounds__(256) void pack_qkv_bias(
    const float* __restrict__ bq, const float* __restrict__ bk,
    const float* __restrict__ bv, float* __restrict__ out) {
  int i = blockIdx.x * 256 + threadIdx.x;   // 0 .. L*3072-1
  int l = i / QKV_N, j = i % QKV_N;
  float v = (j < D_MODEL) ? bq[l * D_MODEL + j]
          : (j < 2 * D_MODEL) ? bk[l * D_MODEL + j - D_MODEL]
          : bv[l * D_MODEL + j - 2 * D_MODEL];
  out[i] = v;
}

// ---------------- bf16 MFMA GEMM: C[M,N] = A[M,K] @ Bt[N,K]^T ----------------
// m97 structure: 128x128 tile, 256 thr = 4 waves (2x2), each wave 64x64 = 4x4
// fragments of 16x16x32. global_load_lds width-16 staging, BK=32.
// OUT_MODE: 0 = bf16 out (+bias), 1 = fp32 residual += (+bias), 2 = fp32 out.
template <int OUT_MODE, bool GELU_ACT>
__global__ __launch_bounds__(256) void gemm_bf16(
    const u16* __restrict__ A, const u16* __restrict__ Bt,
    const float* __restrict__ bias, float* __restrict__ Cf,
    u16* __restrict__ Cb, int M, int N, int K) {
  __shared__ __align__(16) u16 As[128 * 32];
  __shared__ __align__(16) u16 Bs[128 * 32];
  const int tid = threadIdx.x;
  const int wid = tid >> 6;
  const int lane = tid & 63;
  const int wr = wid >> 1, wc = wid & 1;
  const int bm = blockIdx.y, bn = blockIdx.x;
  // staging source: wave wid loads rows [wid*32, wid*32+32); 4 lanes per row.
  const u16* Ag = A + (size_t)(bm * 128 + wid * 32 + (lane >> 2)) * K + (lane & 3) * 8;
  const u16* Bg = Bt + (size_t)(bn * 128 + wid * 32 + (lane >> 2)) * K + (lane & 3) * 8;
  u16* Asw = As + wid * 1024;   // wave-uniform LDS dest (HW adds lane*16B)
  u16* Bsw = Bs + wid * 1024;
  f32x4 acc[4][4] = {};
  for (int k0 = 0; k0 < K; k0 += 32) {
    g2l16(Ag + k0, Asw);
    g2l16(Ag + k0 + (size_t)16 * K, Asw + 512);
    g2l16(Bg + k0, Bsw);
    g2l16(Bg + k0 + (size_t)16 * K, Bsw + 512);
    __syncthreads();
    short8v a[4], b[4];
    const int fr = lane & 15;
    const int ko = (lane >> 4) * 8;
#pragma unroll
    for (int m = 0; m < 4; ++m)
      a[m] = *(const short8v*)&As[(wr * 64 + m * 16 + fr) * 32 + ko];
#pragma unroll
    for (int n = 0; n < 4; ++n)
      b[n] = *(const short8v*)&Bs[(wc * 64 + n * 16 + fr) * 32 + ko];
#pragma unroll
    for (int m = 0; m < 4; ++m)
#pragma unroll
      for (int n = 0; n < 4; ++n)
        acc[m][n] = __builtin_amdgcn_mfma_f32_16x16x32_bf16(a[m], b[n], acc[m][n], 0, 0, 0);
    __syncthreads();
  }
  // epilogue: C/D layout col=lane&15, row=(lane>>4)*4+reg (m89/m91-verified)
  const int row0 = bm * 128 + wr * 64 + (lane >> 4) * 4;
  const int col0 = bn * 128 + wc * 64 + (lane & 15);
#pragma unroll
  for (int m = 0; m < 4; ++m) {
#pragma unroll
    for (int n = 0; n < 4; ++n) {
      const int col = col0 + n * 16;
      float bv = (OUT_MODE == 2) ? 0.f : bias[col];
#pragma unroll
      for (int r = 0; r < 4; ++r) {
        const int row = row0 + m * 16 + r;
        float v = acc[m][n][r] + bv;
        if (GELU_ACT) v = 0.5f * v * (1.0f + erff(v * 0.70710678118f));
        size_t idx = (size_t)row * N + col;
        if (OUT_MODE == 0) Cb[idx] = f2b(v);
        else if (OUT_MODE == 1) Cf[idx] += v;
        else Cf[idx] = v;
      }
    }
  }
}

// ---------------- fused causal attention (bf16 in/out, fp32 math) ----------------
// one wave per (b,h,qpos); qkv packed [ROWS][3072]: q|k|v each D_MODEL wide.
__global__ __launch_bounds__(64) void attn_kernel(
    const u16* __restrict__ qkv, u16* __restrict__ ctx) {
  const int qpos = blockIdx.x;
  const int bh = blockIdx.y;
  const int b = bh >> 4, h = bh & 15;
  const int lane = threadIdx.x;
  __shared__ float qs[64];
  __shared__ float sc[S_LEN];
  __shared__ float Ks[64][65];
  const size_t rb = (size_t)b * S_LEN;
  const int qc = h * 64, kc = D_MODEL + h * 64, vc = 2 * D_MODEL + h * 64;
  qs[lane] = b2f(qkv[(rb + qpos) * QKV_N + qc + lane]);
#pragma unroll
  for (int i = 0; i < S_LEN / 64; ++i) sc[lane + i * 64] = -1e9f;
  __syncthreads();
  const float scale = 0.125f;  // 1/sqrt(64)
  int ntile = (qpos >> 6) + 1;
  for (int t = 0; t < ntile; ++t) {
    int k0 = t * 64;
#pragma unroll 8
    for (int j = 0; j < 64; ++j)
      Ks[j][lane] = b2f(qkv[(rb + k0 + j) * QKV_N + kc + lane]);
    __syncthreads();
    int kk = k0 + lane;
    if (kk <= qpos) {
      float s = 0.f;
#pragma unroll
      for (int d = 0; d < 64; ++d) s += qs[d] * Ks[lane][d];
      sc[kk] = s * scale;
    }
    __syncthreads();
  }
  float m = -1e30f;
#pragma unroll
  for (int i = 0; i < S_LEN / 64; ++i) m = fmaxf(m, sc[lane + i * 64]);
#pragma unroll
  for (int off = 32; off; off >>= 1) m = fmaxf(m, __shfl_xor(m, off, 64));
  float sum = 0.f;
#pragma unroll
  for (int i = 0; i < S_LEN / 64; ++i) {
    float e = expf(sc[lane + i * 64] - m);
    sc[lane + i * 64] = e;
    sum += e;
  }
#pragma unroll
  for (int off = 32; off; off >>= 1) sum += __shfl_xor(sum, off, 64);
  __syncthreads();
  float inv = 1.f / sum;
  float acc = 0.f;
  int kmax = qpos + 1;
  for (int kk2 = 0; kk2 < kmax; ++kk2)
    acc += sc[kk2] * b2f(qkv[(rb + kk2) * QKV_N + vc + lane]);
  ctx[(rb + qpos) * D_MODEL + h * 64 + lane] = f2b(acc * inv);
}

// ---------------- launch ----------------
extern "C" void kernel_launch(void* const* d_in, const int* in_sizes, int n_in,
                              void* d_out, int out_size, void* d_ws, size_t ws_size,
                              hipStream_t stream) {
  const int* x = (const int*)d_in[0];
  const float* tok_emb = (const float*)d_in[1];
  const float* wq = (const float*)d_in[2];
  const float* bq = (const float*)d_in[3];
  const float* wk = (const float*)d_in[4];
  const float* bk = (const float*)d_in[5];
  const float* wv = (const float*)d_in[6];
  const float* bv = (const float*)d_in[7];
  const float* wo = (const float*)d_in[8];
  const float* bo = (const float*)d_in[9];
  const float* ln1_g = (const float*)d_in[10];
  const float* ln1_b = (const float*)d_in[11];
  const float* w1 = (const float*)d_in[12];
  const float* b1 = (const float*)d_in[13];
  const float* w2 = (const float*)d_in[14];
  const float* b2 = (const float*)d_in[15];
  const float* ln2_g = (const float*)d_in[16];
  const float* ln2_b = (const float*)d_in[17];
  const float* lnf_g = (const float*)d_in[18];
  const float* lnf_b = (const float*)d_in[19];
  const float* lm_w = (const float*)d_in[20];

  char* w = (char*)d_ws;
  float* h    = (float*)(w);                      // 8 MB   fp32 residual
  u16*  hn    = (u16*)(w + (8ll << 20));          // 4 MB   bf16 LN out
  u16*  qkvb  = (u16*)(w + (12ll << 20));         // 12 MB  bf16 packed qkv
  u16*  cbuf  = (u16*)(w + (24ll << 20));         // 4 MB   bf16 attn ctx
  u16*  ff    = qkvb;                             // 16 MB  alias qkv+cbuf (dead by FF1)
  u16*  wqkvT = (u16*)(w + (28ll << 20));         // 36 MB  [L][3072][1024]
  u16*  woT   = (u16*)(w + (64ll << 20));         // 12 MB  [L][1024][1024]
  u16*  w1T   = (u16*)(w + (76ll << 20));         // 48 MB  [L][4096][1024]
  u16*  w2T   = (u16*)(w + (124ll << 20));        // 48 MB  [L][1024][4096]
  u16*  lmT   = (u16*)(w + (172ll << 20));        // 62.5MB [32000][1024]
  float* bqkv = (float*)(w + (235ll << 20));      // 72 KB  [L][3072]

  // ---- weight prep (every launch; deterministic) ----
  const size_t DD = (size_t)D_MODEL * D_MODEL;
  const size_t DDF = (size_t)D_MODEL * DF_DIM;
  for (int l = 0; l < L_NUM; ++l) {
    u16* qt = wqkvT + (size_t)l * QKV_N * D_MODEL;
    transpose_cvt<<<dim3(32, 32), 256, 0, stream>>>(wq + l * DD, qt, D_MODEL, D_MODEL);
    transpose_cvt<<<dim3(32, 32), 256, 0, stream>>>(wk + l * DD, qt + DD, D_MODEL, D_MODEL);
    transpose_cvt<<<dim3(32, 32), 256, 0, stream>>>(wv + l * DD, qt + 2 * DD, D_MODEL, D_MODEL);
    transpose_cvt<<<dim3(32, 32), 256, 0, stream>>>(wo + l * DD, woT + l * DD, D_MODEL, D_MODEL);
    transpose_cvt<<<dim3(128, 32), 256, 0, stream>>>(w1 + l * DDF, w1T + l * DDF, D_MODEL, DF_DIM);
    transpose_cvt<<<dim3(32, 128), 256, 0, stream>>>(w2 + l * DDF, w2T + l * DDF, DF_DIM, D_MODEL);
  }
  transpose_cvt<<<dim3(V_SIZE / 32, 32), 256, 0, stream>>>(lm_w, lmT, D_MODEL, V_SIZE);
  pack_qkv_bias<<<L_NUM * QKV_N / 256, 256, 0, stream>>>(bq, bk, bv, bqkv);

  // ---- forward ----
  embed_kernel<<<ROWS, 256, 0, stream>>>(x, tok_emb, h);

  const dim3 gQKV(QKV_N / 128, ROWS / 128);
  const dim3 gD(D_MODEL / 128, ROWS / 128);
  const dim3 gF(DF_DIM / 128, ROWS / 128);
  const dim3 gV(V_SIZE / 128, ROWS / 128);
  for (int l = 0; l < L_NUM; ++l) {
    layernorm_kernel<<<ROWS, 256, 0, stream>>>(h, ln1_g + l * D_MODEL, ln1_b + l * D_MODEL, hn);
    gemm_bf16<0, false><<<gQKV, 256, 0, stream>>>(
        hn, wqkvT + (size_t)l * QKV_N * D_MODEL, bqkv + l * QKV_N, nullptr, qkvb,
        ROWS, QKV_N, D_MODEL);
    attn_kernel<<<dim3(S_LEN, B_SZ * H_NUM), 64, 0, stream>>>(qkvb, cbuf);
    gemm_bf16<1, false><<<gD, 256, 0, stream>>>(
        cbuf, woT + l * DD, bo + l * D_MODEL, h, nullptr, ROWS, D_MODEL, D_MODEL);
    layernorm_kernel<<<ROWS, 256, 0, stream>>>(h, ln2_g + l * D_MODEL, ln2_b + l * D_MODEL, hn);
    gemm_bf16<0, true><<<gF, 256, 0, stream>>>(
        hn, w1T + l * DDF, b1 + l * DF_DIM, nullptr, ff, ROWS, DF_DIM, D_MODEL);
    gemm_bf16<1, false><<<gD, 256, 0, stream>>>(
        ff, w2T + l * DDF, b2 + l * D_MODEL, h, nullptr, ROWS, D_MODEL, DF_DIM);
  }
  layernorm_kernel<<<ROWS, 256, 0, stream>>>(h, lnf_g, lnf_b, hn);
  gemm_bf16<2, false><<<gV, 256, 0, stream>>>(
      hn, lmT, nullptr, (float*)d_out, nullptr, ROWS, V_SIZE, D_MODEL);
}

// Round 3
// 2120.875 us; speedup vs baseline: 5.4763x; 2.1953x over previous
//
#include <hip/hip_runtime.h>
#include <hip/hip_bf16.h>
#include <math.h>

// GPT forward. V=32000 L=6 H=16 D=1024 S=512 B=4, DK=64, DF=4096.
// Round 2: flash-style MFMA attention (QBLK=128, KVBLK=64, online softmax).
#define V_SIZE 32000
#define L_NUM 6
#define H_NUM 16
#define D_MODEL 1024
#define S_LEN 512
#define B_SZ 4
#define DF_DIM 4096
#define ROWS (B_SZ * S_LEN)   // 2048
#define QKV_N (3 * D_MODEL)   // 3072
#define QBLK 128
#define KVBLK 64

typedef unsigned short u16;
typedef __attribute__((ext_vector_type(8))) short short8v;   // 8 bf16
typedef __attribute__((ext_vector_type(4))) float f32x4;

__device__ __forceinline__ float b2f(u16 b) {
  union { float f; unsigned u; } c; c.u = ((unsigned)b) << 16; return c.f;
}
__device__ __forceinline__ u16 f2b(float f) {
  __hip_bfloat16 h = __float2bfloat16(f);
  union { __hip_bfloat16 h; u16 u; } c; c.h = h; return c.u;
}
__device__ __forceinline__ void g2l16(const void* g, void* l) {
  __builtin_amdgcn_global_load_lds(
      (const __attribute__((address_space(1))) void*)g,
      (__attribute__((address_space(3))) void*)l, 16, 0, 0);
}

// ---------------- embedding + sinusoidal PE (fp32 out) ----------------
__global__ __launch_bounds__(256) void embed_kernel(
    const int* __restrict__ x, const float* __restrict__ tok_emb,
    float* __restrict__ h) {
  int row = blockIdx.x;
  int s = row % S_LEN;
  int tok = x[row];
  const float* te = tok_emb + (size_t)tok * D_MODEL;
  float* hr = h + (size_t)row * D_MODEL;
  float pos = (float)s;
  const float c = 9.210340371976184f / (float)D_MODEL;  // ln(10000)/D
#pragma unroll
  for (int i = 0; i < D_MODEL / 256; ++i) {
    int d = threadIdx.x + i * 256;
    float freq = expf(-(float)(d & ~1) * c);
    float ang = pos * freq;
    float pe = (d & 1) ? cosf(ang) : sinf(ang);
    hr[d] = te[d] + pe;
  }
}

// ---------------- layernorm: fp32 in -> bf16 out ----------------
__global__ __launch_bounds__(256) void layernorm_kernel(
    const float* __restrict__ in, const float* __restrict__ g,
    const float* __restrict__ b, u16* __restrict__ out) {
  int row = blockIdx.x;
  const float* xr = in + (size_t)row * D_MODEL;
  float vals[D_MODEL / 256];
  float s1 = 0.f, s2 = 0.f;
#pragma unroll
  for (int i = 0; i < D_MODEL / 256; ++i) {
    int d = threadIdx.x + i * 256;
    float v = xr[d];
    vals[i] = v;
    s1 += v;
    s2 += v * v;
  }
#pragma unroll
  for (int off = 32; off; off >>= 1) {
    s1 += __shfl_xor(s1, off, 64);
    s2 += __shfl_xor(s2, off, 64);
  }
  __shared__ float w1s[4], w2s[4];
  int wid = threadIdx.x >> 6;
  if ((threadIdx.x & 63) == 0) { w1s[wid] = s1; w2s[wid] = s2; }
  __syncthreads();
  s1 = w1s[0] + w1s[1] + w1s[2] + w1s[3];
  s2 = w2s[0] + w2s[1] + w2s[2] + w2s[3];
  float mu = s1 * (1.0f / D_MODEL);
  float var = s2 * (1.0f / D_MODEL) - mu * mu;
  float rstd = rsqrtf(var + 1e-5f);
  u16* orow = out + (size_t)row * D_MODEL;
#pragma unroll
  for (int i = 0; i < D_MODEL / 256; ++i) {
    int d = threadIdx.x + i * 256;
    orow[d] = f2b((vals[i] - mu) * rstd * g[d] + b[d]);
  }
}

// ---------------- fp32 [K][N] -> bf16 [N][K] transpose ----------------
__global__ __launch_bounds__(256) void transpose_cvt(
    const float* __restrict__ W, u16* __restrict__ Wt, int K, int N) {
  __shared__ float t[32][33];
  const int n0 = blockIdx.x * 32, k0 = blockIdx.y * 32;
  const int tx = threadIdx.x & 31, ty = threadIdx.x >> 5;
#pragma unroll
  for (int i = 0; i < 32; i += 8)
    t[ty + i][tx] = W[(size_t)(k0 + ty + i) * N + n0 + tx];
  __syncthreads();
#pragma unroll
  for (int i = 0; i < 32; i += 8)
    Wt[(size_t)(n0 + ty + i) * K + k0 + tx] = f2b(t[tx][ty + i]);
}

// ---------------- pack bq|bk|bv -> [L][3072] ----------------
__global__ __launch_bounds__(256) void pack_qkv_bias(
    const float* __restrict__ bq, const float* __restrict__ bk,
    const float* __restrict__ bv, float* __restrict__ out) {
  int i = blockIdx.x * 256 + threadIdx.x;   // 0 .. L*3072-1
  int l = i / QKV_N, j = i % QKV_N;
  float v = (j < D_MODEL) ? bq[l * D_MODEL + j]
          : (j < 2 * D_MODEL) ? bk[l * D_MODEL + j - D_MODEL]
          : bv[l * D_MODEL + j - 2 * D_MODEL];
  out[i] = v;
}

// ---------------- bf16 MFMA GEMM: C[M,N] = A[M,K] @ Bt[N,K]^T ----------------
template <int OUT_MODE, bool GELU_ACT>
__global__ __launch_bounds__(256) void gemm_bf16(
    const u16* __restrict__ A, const u16* __restrict__ Bt,
    const float* __restrict__ bias, float* __restrict__ Cf,
    u16* __restrict__ Cb, int M, int N, int K) {
  __shared__ __align__(16) u16 As[128 * 32];
  __shared__ __align__(16) u16 Bs[128 * 32];
  const int tid = threadIdx.x;
  const int wid = tid >> 6;
  const int lane = tid & 63;
  const int wr = wid >> 1, wc = wid & 1;
  const int bm = blockIdx.y, bn = blockIdx.x;
  const u16* Ag = A + (size_t)(bm * 128 + wid * 32 + (lane >> 2)) * K + (lane & 3) * 8;
  const u16* Bg = Bt + (size_t)(bn * 128 + wid * 32 + (lane >> 2)) * K + (lane & 3) * 8;
  u16* Asw = As + wid * 1024;
  u16* Bsw = Bs + wid * 1024;
  f32x4 acc[4][4] = {};
  for (int k0 = 0; k0 < K; k0 += 32) {
    g2l16(Ag + k0, Asw);
    g2l16(Ag + k0 + (size_t)16 * K, Asw + 512);
    g2l16(Bg + k0, Bsw);
    g2l16(Bg + k0 + (size_t)16 * K, Bsw + 512);
    __syncthreads();
    short8v a[4], b[4];
    const int fr = lane & 15;
    const int ko = (lane >> 4) * 8;
#pragma unroll
    for (int m = 0; m < 4; ++m)
      a[m] = *(const short8v*)&As[(wr * 64 + m * 16 + fr) * 32 + ko];
#pragma unroll
    for (int n = 0; n < 4; ++n)
      b[n] = *(const short8v*)&Bs[(wc * 64 + n * 16 + fr) * 32 + ko];
#pragma unroll
    for (int m = 0; m < 4; ++m)
#pragma unroll
      for (int n = 0; n < 4; ++n)
        acc[m][n] = __builtin_amdgcn_mfma_f32_16x16x32_bf16(a[m], b[n], acc[m][n], 0, 0, 0);
    __syncthreads();
  }
  const int row0 = bm * 128 + wr * 64 + (lane >> 4) * 4;
  const int col0 = bn * 128 + wc * 64 + (lane & 15);
#pragma unroll
  for (int m = 0; m < 4; ++m) {
#pragma unroll
    for (int n = 0; n < 4; ++n) {
      const int col = col0 + n * 16;
      float bv = (OUT_MODE == 2) ? 0.f : bias[col];
#pragma unroll
      for (int r = 0; r < 4; ++r) {
        const int row = row0 + m * 16 + r;
        float v = acc[m][n][r] + bv;
        if (GELU_ACT) v = 0.5f * v * (1.0f + erff(v * 0.70710678118f));
        size_t idx = (size_t)row * N + col;
        if (OUT_MODE == 0) Cb[idx] = f2b(v);
        else if (OUT_MODE == 1) Cf[idx] += v;
        else Cf[idx] = v;
      }
    }
  }
}

// ---------------- flash-style MFMA attention ----------------
// grid (S/QBLK=4, B*H=64), 256 thr = 4 waves; wave owns 32 q-rows.
// qkv packed [ROWS][3072] bf16 (q|k|v). ctx bf16 [ROWS][D].
__global__ __launch_bounds__(256) void attn_mfma(
    const u16* __restrict__ qkv, u16* __restrict__ ctx) {
  __shared__ __align__(16) u16 smem[18432];
  u16 (*Qs)[72] = (u16(*)[72])smem;             // [128][72]
  u16 (*Ks)[72] = (u16(*)[72])(smem + 9216);    // [64][72]
  u16 (*Vs)[72] = (u16(*)[72])(smem + 13824);   // [64][72]  V^T: [d][k]
  const int qt = blockIdx.x, bh = blockIdx.y;
  const int b = bh >> 4, h = bh & 15;
  const int tid = threadIdx.x, wid = tid >> 6, lane = tid & 63;
  const int fr = lane & 15, ko = (lane >> 4) * 8;
  u16 (*Ps)[72] = (u16(*)[72])(smem + wid * 2304);  // [32][72]/wave, aliases Qs
  const size_t rb = (size_t)b * S_LEN;
  const int q0 = qt * QBLK;
  const int hq = h * 64;
  // stage Q tile (128 rows x 64 cols)
#pragma unroll
  for (int i = 0; i < 4; ++i) {
    int e = tid + i * 256, r = e >> 3, c = (e & 7) * 8;
    *(short8v*)&Qs[r][c] = *(const short8v*)&qkv[(rb + q0 + r) * QKV_N + hq + c];
  }
  __syncthreads();
  short8v qf[2][2];
#pragma unroll
  for (int m = 0; m < 2; ++m)
#pragma unroll
    for (int ks = 0; ks < 2; ++ks)
      qf[m][ks] = *(const short8v*)&Qs[wid * 32 + m * 16 + fr][ks * 32 + ko];
  f32x4 acc_o[2][4] = {};
  float mrow[2][4], lrow[2][4];
#pragma unroll
  for (int m = 0; m < 2; ++m)
#pragma unroll
    for (int r = 0; r < 4; ++r) { mrow[m][r] = -1e30f; lrow[m][r] = 0.f; }
  const int nt = 2 * qt + 2;
  for (int t = 0; t < nt; ++t) {
    const int k0 = t * KVBLK;
    __syncthreads();   // Ks/Vs reads (prev iter) + Qs->Ps alias done
#pragma unroll
    for (int i = 0; i < 2; ++i) {
      int e = tid + i * 256, r = e >> 3, c = (e & 7) * 8;
      *(short8v*)&Ks[r][c] =
          *(const short8v*)&qkv[(rb + k0 + r) * QKV_N + D_MODEL + hq + c];
      short8v vv = *(const short8v*)&qkv[(rb + k0 + r) * QKV_N + 2 * D_MODEL + hq + c];
#pragma unroll
      for (int j = 0; j < 8; ++j) Vs[c + j][r] = (u16)vv[j];
    }
    __syncthreads();
    // S = Q K^T
    f32x4 s[2][4] = {};
#pragma unroll
    for (int n = 0; n < 4; ++n)
#pragma unroll
      for (int ks = 0; ks < 2; ++ks) {
        short8v kf = *(const short8v*)&Ks[n * 16 + fr][ks * 32 + ko];
#pragma unroll
        for (int m = 0; m < 2; ++m)
          s[m][n] = __builtin_amdgcn_mfma_f32_16x16x32_bf16(qf[m][ks], kf, s[m][n], 0, 0, 0);
      }
    // mask + online softmax (row on 16-lane group; C/D: col=lane&15, row=(lane>>4)*4+r)
#pragma unroll
    for (int m = 0; m < 2; ++m) {
      const int rbase = q0 + wid * 32 + m * 16 + (lane >> 4) * 4;
#pragma unroll
      for (int r = 0; r < 4; ++r) {
        const int row_g = rbase + r;
        float vmax = -1e30f;
#pragma unroll
        for (int n = 0; n < 4; ++n) {
          float v = s[m][n][r] * 0.125f;
          if (k0 + n * 16 + fr > row_g) v = -1e30f;
          s[m][n][r] = v;
          vmax = fmaxf(vmax, v);
        }
#pragma unroll
        for (int off = 1; off < 16; off <<= 1) vmax = fmaxf(vmax, __shfl_xor(vmax, off, 64));
        const float mnew = fmaxf(mrow[m][r], vmax);
        const float sc = expf(mrow[m][r] - mnew);
        mrow[m][r] = mnew;
        float ssum = 0.f;
#pragma unroll
        for (int n = 0; n < 4; ++n) {
          float p = expf(s[m][n][r] - mnew);
          s[m][n][r] = p;
          ssum += p;
        }
#pragma unroll
        for (int off = 1; off < 16; off <<= 1) ssum += __shfl_xor(ssum, off, 64);
        lrow[m][r] = lrow[m][r] * sc + ssum;
#pragma unroll
        for (int n = 0; n < 4; ++n) {
          acc_o[m][n][r] *= sc;
          Ps[m * 16 + (lane >> 4) * 4 + r][n * 16 + fr] = f2b(s[m][n][r]);
        }
      }
    }
    // O += P V  (wave-private Ps; compiler orders same-wave LDS RAW)
#pragma unroll
    for (int ks = 0; ks < 2; ++ks) {
      short8v pf[2];
#pragma unroll
      for (int m = 0; m < 2; ++m) pf[m] = *(const short8v*)&Ps[m * 16 + fr][ks * 32 + ko];
#pragma unroll
      for (int n = 0; n < 4; ++n) {
        short8v vf = *(const short8v*)&Vs[n * 16 + fr][ks * 32 + ko];
#pragma unroll
        for (int m = 0; m < 2; ++m)
          acc_o[m][n] = __builtin_amdgcn_mfma_f32_16x16x32_bf16(pf[m], vf, acc_o[m][n], 0, 0, 0);
      }
    }
  }
  // epilogue
#pragma unroll
  for (int m = 0; m < 2; ++m)
#pragma unroll
    for (int r = 0; r < 4; ++r) {
      const int row_g = q0 + wid * 32 + m * 16 + (lane >> 4) * 4 + r;
      const float inv = 1.0f / lrow[m][r];
#pragma unroll
      for (int n = 0; n < 4; ++n)
        ctx[(rb + row_g) * D_MODEL + hq + n * 16 + fr] = f2b(acc_o[m][n][r] * inv);
    }
}

// ---------------- launch ----------------
extern "C" void kernel_launch(void* const* d_in, const int* in_sizes, int n_in,
                              void* d_out, int out_size, void* d_ws, size_t ws_size,
                              hipStream_t stream) {
  const int* x = (const int*)d_in[0];
  const float* tok_emb = (const float*)d_in[1];
  const float* wq = (const float*)d_in[2];
  const float* bq = (const float*)d_in[3];
  const float* wk = (const float*)d_in[4];
  const float* bk = (const float*)d_in[5];
  const float* wv = (const float*)d_in[6];
  const float* bv = (const float*)d_in[7];
  const float* wo = (const float*)d_in[8];
  const float* bo = (const float*)d_in[9];
  const float* ln1_g = (const float*)d_in[10];
  const float* ln1_b = (const float*)d_in[11];
  const float* w1 = (const float*)d_in[12];
  const float* b1 = (const float*)d_in[13];
  const float* w2 = (const float*)d_in[14];
  const float* b2 = (const float*)d_in[15];
  const float* ln2_g = (const float*)d_in[16];
  const float* ln2_b = (const float*)d_in[17];
  const float* lnf_g = (const float*)d_in[18];
  const float* lnf_b = (const float*)d_in[19];
  const float* lm_w = (const float*)d_in[20];

  char* w = (char*)d_ws;
  float* h    = (float*)(w);                      // 8 MB   fp32 residual
  u16*  hn    = (u16*)(w + (8ll << 20));          // 4 MB   bf16 LN out
  u16*  qkvb  = (u16*)(w + (12ll << 20));         // 12 MB  bf16 packed qkv
  u16*  cbuf  = (u16*)(w + (24ll << 20));         // 4 MB   bf16 attn ctx
  u16*  ff    = qkvb;                             // 16 MB  alias qkv+cbuf
  u16*  wqkvT = (u16*)(w + (28ll << 20));         // 36 MB  [L][3072][1024]
  u16*  woT   = (u16*)(w + (64ll << 20));         // 12 MB  [L][1024][1024]
  u16*  w1T   = (u16*)(w + (76ll << 20));         // 48 MB  [L][4096][1024]
  u16*  w2T   = (u16*)(w + (124ll << 20));        // 48 MB  [L][1024][4096]
  u16*  lmT   = (u16*)(w + (172ll << 20));        // 62.5MB [32000][1024]
  float* bqkv = (float*)(w + (235ll << 20));      // 72 KB  [L][3072]

  const size_t DD = (size_t)D_MODEL * D_MODEL;
  const size_t DDF = (size_t)D_MODEL * DF_DIM;
  for (int l = 0; l < L_NUM; ++l) {
    u16* qt = wqkvT + (size_t)l * QKV_N * D_MODEL;
    transpose_cvt<<<dim3(32, 32), 256, 0, stream>>>(wq + l * DD, qt, D_MODEL, D_MODEL);
    transpose_cvt<<<dim3(32, 32), 256, 0, stream>>>(wk + l * DD, qt + DD, D_MODEL, D_MODEL);
    transpose_cvt<<<dim3(32, 32), 256, 0, stream>>>(wv + l * DD, qt + 2 * DD, D_MODEL, D_MODEL);
    transpose_cvt<<<dim3(32, 32), 256, 0, stream>>>(wo + l * DD, woT + l * DD, D_MODEL, D_MODEL);
    transpose_cvt<<<dim3(128, 32), 256, 0, stream>>>(w1 + l * DDF, w1T + l * DDF, D_MODEL, DF_DIM);
    transpose_cvt<<<dim3(32, 128), 256, 0, stream>>>(w2 + l * DDF, w2T + l * DDF, DF_DIM, D_MODEL);
  }
  transpose_cvt<<<dim3(V_SIZE / 32, 32), 256, 0, stream>>>(lm_w, lmT, D_MODEL, V_SIZE);
  pack_qkv_bias<<<L_NUM * QKV_N / 256, 256, 0, stream>>>(bq, bk, bv, bqkv);

  embed_kernel<<<ROWS, 256, 0, stream>>>(x, tok_emb, h);

  const dim3 gQKV(QKV_N / 128, ROWS / 128);
  const dim3 gD(D_MODEL / 128, ROWS / 128);
  const dim3 gF(DF_DIM / 128, ROWS / 128);
  const dim3 gV(V_SIZE / 128, ROWS / 128);
  for (int l = 0; l < L_NUM; ++l) {
    layernorm_kernel<<<ROWS, 256, 0, stream>>>(h, ln1_g + l * D_MODEL, ln1_b + l * D_MODEL, hn);
    gemm_bf16<0, false><<<gQKV, 256, 0, stream>>>(
        hn, wqkvT + (size_t)l * QKV_N * D_MODEL, bqkv + l * QKV_N, nullptr, qkvb,
        ROWS, QKV_N, D_MODEL);
    attn_mfma<<<dim3(S_LEN / QBLK, B_SZ * H_NUM), 256, 0, stream>>>(qkvb, cbuf);
    gemm_bf16<1, false><<<gD, 256, 0, stream>>>(
        cbuf, woT + l * DD, bo + l * D_MODEL, h, nullptr, ROWS, D_MODEL, D_MODEL);
    layernorm_kernel<<<ROWS, 256, 0, stream>>>(h, ln2_g + l * D_MODEL, ln2_b + l * D_MODEL, hn);
    gemm_bf16<0, true><<<gF, 256, 0, stream>>>(
        hn, w1T + l * DDF, b1 + l * DF_DIM, nullptr, ff, ROWS, DF_DIM, D_MODEL);
    gemm_bf16<1, false><<<gD, 256, 0, stream>>>(
        ff, w2T + l * DDF, b2 + l * D_MODEL, h, nullptr, ROWS, D_MODEL, DF_DIM);
  }
  layernorm_kernel<<<ROWS, 256, 0, stream>>>(h, lnf_g, lnf_b, hn);
  gemm_bf16<2, false><<<gV, 256, 0, stream>>>(
      hn, lmT, nullptr, (float*)d_out, nullptr, ROWS, V_SIZE, D_MODEL);
}

// Round 4
// 1867.316 us; speedup vs baseline: 6.2200x; 1.1358x over previous
//
#include <hip/hip_runtime.h>
#include <hip/hip_bf16.h>
#include <math.h>

// GPT forward. V=32000 L=6 H=16 D=1024 S=512 B=4, DK=64, DF=4096.
// Round 3: XCD-swizzled bm-fastest 1-D grids, TM=64 tile for N=1024 GEMMs,
// wave-per-row vectorized LayerNorm, batched weight-prep launches.
#define V_SIZE 32000
#define L_NUM 6
#define H_NUM 16
#define D_MODEL 1024
#define S_LEN 512
#define B_SZ 4
#define DF_DIM 4096
#define ROWS (B_SZ * S_LEN)   // 2048
#define QKV_N (3 * D_MODEL)   // 3072
#define QBLK 128
#define KVBLK 64

typedef unsigned short u16;
typedef __attribute__((ext_vector_type(8))) short short8v;   // 8 bf16
typedef __attribute__((ext_vector_type(4))) float f32x4;

__device__ __forceinline__ float b2f(u16 b) {
  union { float f; unsigned u; } c; c.u = ((unsigned)b) << 16; return c.f;
}
__device__ __forceinline__ u16 f2b(float f) {
  __hip_bfloat16 h = __float2bfloat16(f);
  union { __hip_bfloat16 h; u16 u; } c; c.h = h; return c.u;
}
__device__ __forceinline__ void g2l16(const void* g, void* l) {
  __builtin_amdgcn_global_load_lds(
      (const __attribute__((address_space(1))) void*)g,
      (__attribute__((address_space(3))) void*)l, 16, 0, 0);
}

// ---------------- embedding + sinusoidal PE (fp32 out) ----------------
__global__ __launch_bounds__(256) void embed_kernel(
    const int* __restrict__ x, const float* __restrict__ tok_emb,
    float* __restrict__ h) {
  int row = blockIdx.x;
  int s = row % S_LEN;
  int tok = x[row];
  const float* te = tok_emb + (size_t)tok * D_MODEL;
  float* hr = h + (size_t)row * D_MODEL;
  float pos = (float)s;
  const float c = 9.210340371976184f / (float)D_MODEL;  // ln(10000)/D
#pragma unroll
  for (int i = 0; i < D_MODEL / 256; ++i) {
    int d = threadIdx.x + i * 256;
    float freq = expf(-(float)(d & ~1) * c);
    float ang = pos * freq;
    float pe = (d & 1) ? cosf(ang) : sinf(ang);
    hr[d] = te[d] + pe;
  }
}

// ---------------- layernorm: wave per row, float4 loads, bf16 out ----------------
__global__ __launch_bounds__(256) void layernorm_kernel(
    const float* __restrict__ in, const float* __restrict__ g,
    const float* __restrict__ b, u16* __restrict__ out) {
  const int row = blockIdx.x * 4 + (threadIdx.x >> 6);
  const int lane = threadIdx.x & 63;
  const float4* xr = (const float4*)(in + (size_t)row * D_MODEL);
  float4 v[4];
  float s1 = 0.f, s2 = 0.f;
#pragma unroll
  for (int i = 0; i < 4; ++i) {
    float4 t = xr[lane + i * 64];
    v[i] = t;
    s1 += t.x + t.y + t.z + t.w;
    s2 += t.x * t.x + t.y * t.y + t.z * t.z + t.w * t.w;
  }
#pragma unroll
  for (int off = 32; off; off >>= 1) {
    s1 += __shfl_xor(s1, off, 64);
    s2 += __shfl_xor(s2, off, 64);
  }
  const float mu = s1 * (1.0f / D_MODEL);
  const float var = s2 * (1.0f / D_MODEL) - mu * mu;
  const float rstd = rsqrtf(var + 1e-5f);
  u16* orow = out + (size_t)row * D_MODEL;
#pragma unroll
  for (int i = 0; i < 4; ++i) {
    const int d = (lane + i * 64) * 4;
    const float4 gv = *(const float4*)&g[d];
    const float4 bv = *(const float4*)&b[d];
    u16 o0 = f2b((v[i].x - mu) * rstd * gv.x + bv.x);
    u16 o1 = f2b((v[i].y - mu) * rstd * gv.y + bv.y);
    u16 o2 = f2b((v[i].z - mu) * rstd * gv.z + bv.z);
    u16 o3 = f2b((v[i].w - mu) * rstd * gv.w + bv.w);
    uint2 pk;
    pk.x = (unsigned)o0 | ((unsigned)o1 << 16);
    pk.y = (unsigned)o2 | ((unsigned)o3 << 16);
    *(uint2*)&orow[d] = pk;
  }
}

// ---------------- fp32 [K][N] -> bf16 [N][K] transpose (batched over z) ----------------
__global__ __launch_bounds__(256) void transpose_cvt(
    const float* __restrict__ W, u16* __restrict__ Wt, int K, int N,
    long out_stride) {
  __shared__ float t[32][33];
  const float* Wl = W + (size_t)blockIdx.z * K * N;
  u16* Wtl = Wt + (size_t)blockIdx.z * out_stride;
  const int n0 = blockIdx.x * 32, k0 = blockIdx.y * 32;
  const int tx = threadIdx.x & 31, ty = threadIdx.x >> 5;
#pragma unroll
  for (int i = 0; i < 32; i += 8)
    t[ty + i][tx] = Wl[(size_t)(k0 + ty + i) * N + n0 + tx];
  __syncthreads();
#pragma unroll
  for (int i = 0; i < 32; i += 8)
    Wtl[(size_t)(n0 + ty + i) * K + k0 + tx] = f2b(t[tx][ty + i]);
}

// ---------------- pack bq|bk|bv -> [L][3072] ----------------
__global__ __launch_bounds__(256) void pack_qkv_bias(
    const float* __restrict__ bq, const float* __restrict__ bk,
    const float* __restrict__ bv, float* __restrict__ out) {
  int i = blockIdx.x * 256 + threadIdx.x;   // 0 .. L*3072-1
  int l = i / QKV_N, j = i % QKV_N;
  float v = (j < D_MODEL) ? bq[l * D_MODEL + j]
          : (j < 2 * D_MODEL) ? bk[l * D_MODEL + j - D_MODEL]
          : bv[l * D_MODEL + j - 2 * D_MODEL];
  out[i] = v;
}

// ---------------- bf16 MFMA GEMM: C[M,N] = A[M,K] @ Bt[N,K]^T ----------------
// TM x 128 tile, 256 thr = 4 waves (2x2). TM=128: wave 64x64 (4x4 frags).
// TM=64: wave 32x64 (2x4 frags) - for small-N GEMMs needing more blocks.
// 1-D grid, bijective XCD swizzle (m204), bm-fastest for weight-panel L2 reuse.
// OUT_MODE: 0 = bf16 out (+bias), 1 = fp32 residual += (+bias), 2 = fp32 out.
template <int TM, int OUT_MODE, bool GELU_ACT>
__global__ __launch_bounds__(256) void gemm_bf16(
    const u16* __restrict__ A, const u16* __restrict__ Bt,
    const float* __restrict__ bias, float* __restrict__ Cf,
    u16* __restrict__ Cb, int M, int N, int K) {
  constexpr int MF = TM / 32;       // A-frags per wave
  constexpr int ALOADS = TM / 64;   // g2l16 per wave for A per K-step
  __shared__ __align__(16) u16 As[TM * 32];
  __shared__ __align__(16) u16 Bs[128 * 32];
  const int tid = threadIdx.x;
  const int wid = tid >> 6;
  const int lane = tid & 63;
  const int wr = wid >> 1, wc = wid & 1;
  // XCD-bijective swizzle, then bm-fastest decode
  const int nwg = gridDim.x;
  const int id = blockIdx.x;
  const int q = nwg >> 3, r = nwg & 7;
  const int xcd = id & 7, i0 = id >> 3;
  const int swz = (xcd < r ? xcd * (q + 1) : r * (q + 1) + (xcd - r) * q) + i0;
  const int gm = M / TM;
  const int bm = swz % gm, bn = swz / gm;
  const u16* Ag = A + (size_t)(bm * TM + wid * (TM / 4) + (lane >> 2)) * K + (lane & 3) * 8;
  const u16* Bg = Bt + (size_t)(bn * 128 + wid * 32 + (lane >> 2)) * K + (lane & 3) * 8;
  u16* Asw = As + wid * (TM / 4) * 32;
  u16* Bsw = Bs + wid * 1024;
  f32x4 acc[MF][4] = {};
  const int fr = lane & 15;
  const int ko = (lane >> 4) * 8;
  for (int k0 = 0; k0 < K; k0 += 32) {
#pragma unroll
    for (int i = 0; i < ALOADS; ++i)
      g2l16(Ag + k0 + (size_t)(16 * i) * K, Asw + 512 * i);
    g2l16(Bg + k0, Bsw);
    g2l16(Bg + k0 + (size_t)16 * K, Bsw + 512);
    __syncthreads();
    short8v a[MF], b[4];
#pragma unroll
    for (int m = 0; m < MF; ++m)
      a[m] = *(const short8v*)&As[(wr * (TM / 2) + m * 16 + fr) * 32 + ko];
#pragma unroll
    for (int n = 0; n < 4; ++n)
      b[n] = *(const short8v*)&Bs[(wc * 64 + n * 16 + fr) * 32 + ko];
#pragma unroll
    for (int m = 0; m < MF; ++m)
#pragma unroll
      for (int n = 0; n < 4; ++n)
        acc[m][n] = __builtin_amdgcn_mfma_f32_16x16x32_bf16(a[m], b[n], acc[m][n], 0, 0, 0);
    __syncthreads();
  }
  const int row0 = bm * TM + wr * (TM / 2) + (lane >> 4) * 4;
  const int col0 = bn * 128 + wc * 64 + fr;
#pragma unroll
  for (int m = 0; m < MF; ++m) {
#pragma unroll
    for (int n = 0; n < 4; ++n) {
      const int col = col0 + n * 16;
      float bv = (OUT_MODE == 2) ? 0.f : bias[col];
#pragma unroll
      for (int r2 = 0; r2 < 4; ++r2) {
        const int row = row0 + m * 16 + r2;
        float v = acc[m][n][r2] + bv;
        if (GELU_ACT) v = 0.5f * v * (1.0f + erff(v * 0.70710678118f));
        size_t idx = (size_t)row * N + col;
        if (OUT_MODE == 0) Cb[idx] = f2b(v);
        else if (OUT_MODE == 1) Cf[idx] += v;
        else Cf[idx] = v;
      }
    }
  }
}

// ---------------- flash-style MFMA attention ----------------
__global__ __launch_bounds__(256) void attn_mfma(
    const u16* __restrict__ qkv, u16* __restrict__ ctx) {
  __shared__ __align__(16) u16 smem[18432];
  u16 (*Qs)[72] = (u16(*)[72])smem;             // [128][72]
  u16 (*Ks)[72] = (u16(*)[72])(smem + 9216);    // [64][72]
  u16 (*Vs)[72] = (u16(*)[72])(smem + 13824);   // [64][72]  V^T: [d][k]
  const int qt = blockIdx.x, bh = blockIdx.y;
  const int b = bh >> 4, h = bh & 15;
  const int tid = threadIdx.x, wid = tid >> 6, lane = tid & 63;
  const int fr = lane & 15, ko = (lane >> 4) * 8;
  u16 (*Ps)[72] = (u16(*)[72])(smem + wid * 2304);  // [32][72]/wave, aliases Qs
  const size_t rb = (size_t)b * S_LEN;
  const int q0 = qt * QBLK;
  const int hq = h * 64;
#pragma unroll
  for (int i = 0; i < 4; ++i) {
    int e = tid + i * 256, r = e >> 3, c = (e & 7) * 8;
    *(short8v*)&Qs[r][c] = *(const short8v*)&qkv[(rb + q0 + r) * QKV_N + hq + c];
  }
  __syncthreads();
  short8v qf[2][2];
#pragma unroll
  for (int m = 0; m < 2; ++m)
#pragma unroll
    for (int ks = 0; ks < 2; ++ks)
      qf[m][ks] = *(const short8v*)&Qs[wid * 32 + m * 16 + fr][ks * 32 + ko];
  f32x4 acc_o[2][4] = {};
  float mrow[2][4], lrow[2][4];
#pragma unroll
  for (int m = 0; m < 2; ++m)
#pragma unroll
    for (int r = 0; r < 4; ++r) { mrow[m][r] = -1e30f; lrow[m][r] = 0.f; }
  const int nt = 2 * qt + 2;
  for (int t = 0; t < nt; ++t) {
    const int k0 = t * KVBLK;
    __syncthreads();
#pragma unroll
    for (int i = 0; i < 2; ++i) {
      int e = tid + i * 256, r = e >> 3, c = (e & 7) * 8;
      *(short8v*)&Ks[r][c] =
          *(const short8v*)&qkv[(rb + k0 + r) * QKV_N + D_MODEL + hq + c];
      short8v vv = *(const short8v*)&qkv[(rb + k0 + r) * QKV_N + 2 * D_MODEL + hq + c];
#pragma unroll
      for (int j = 0; j < 8; ++j) Vs[c + j][r] = (u16)vv[j];
    }
    __syncthreads();
    f32x4 s[2][4] = {};
#pragma unroll
    for (int n = 0; n < 4; ++n)
#pragma unroll
      for (int ks = 0; ks < 2; ++ks) {
        short8v kf = *(const short8v*)&Ks[n * 16 + fr][ks * 32 + ko];
#pragma unroll
        for (int m = 0; m < 2; ++m)
          s[m][n] = __builtin_amdgcn_mfma_f32_16x16x32_bf16(qf[m][ks], kf, s[m][n], 0, 0, 0);
      }
#pragma unroll
    for (int m = 0; m < 2; ++m) {
      const int rbase = q0 + wid * 32 + m * 16 + (lane >> 4) * 4;
#pragma unroll
      for (int r = 0; r < 4; ++r) {
        const int row_g = rbase + r;
        float vmax = -1e30f;
#pragma unroll
        for (int n = 0; n < 4; ++n) {
          float v = s[m][n][r] * 0.125f;
          if (k0 + n * 16 + fr > row_g) v = -1e30f;
          s[m][n][r] = v;
          vmax = fmaxf(vmax, v);
        }
#pragma unroll
        for (int off = 1; off < 16; off <<= 1) vmax = fmaxf(vmax, __shfl_xor(vmax, off, 64));
        const float mnew = fmaxf(mrow[m][r], vmax);
        const float sc = expf(mrow[m][r] - mnew);
        mrow[m][r] = mnew;
        float ssum = 0.f;
#pragma unroll
        for (int n = 0; n < 4; ++n) {
          float p = expf(s[m][n][r] - mnew);
          s[m][n][r] = p;
          ssum += p;
        }
#pragma unroll
        for (int off = 1; off < 16; off <<= 1) ssum += __shfl_xor(ssum, off, 64);
        lrow[m][r] = lrow[m][r] * sc + ssum;
#pragma unroll
        for (int n = 0; n < 4; ++n) {
          acc_o[m][n][r] *= sc;
          Ps[m * 16 + (lane >> 4) * 4 + r][n * 16 + fr] = f2b(s[m][n][r]);
        }
      }
    }
#pragma unroll
    for (int ks = 0; ks < 2; ++ks) {
      short8v pf[2];
#pragma unroll
      for (int m = 0; m < 2; ++m) pf[m] = *(const short8v*)&Ps[m * 16 + fr][ks * 32 + ko];
#pragma unroll
      for (int n = 0; n < 4; ++n) {
        short8v vf = *(const short8v*)&Vs[n * 16 + fr][ks * 32 + ko];
#pragma unroll
        for (int m = 0; m < 2; ++m)
          acc_o[m][n] = __builtin_amdgcn_mfma_f32_16x16x32_bf16(pf[m], vf, acc_o[m][n], 0, 0, 0);
      }
    }
  }
#pragma unroll
  for (int m = 0; m < 2; ++m)
#pragma unroll
    for (int r = 0; r < 4; ++r) {
      const int row_g = q0 + wid * 32 + m * 16 + (lane >> 4) * 4 + r;
      const float inv = 1.0f / lrow[m][r];
#pragma unroll
      for (int n = 0; n < 4; ++n)
        ctx[(rb + row_g) * D_MODEL + hq + n * 16 + fr] = f2b(acc_o[m][n][r] * inv);
    }
}

// ---------------- launch ----------------
extern "C" void kernel_launch(void* const* d_in, const int* in_sizes, int n_in,
                              void* d_out, int out_size, void* d_ws, size_t ws_size,
                              hipStream_t stream) {
  const int* x = (const int*)d_in[0];
  const float* tok_emb = (const float*)d_in[1];
  const float* wq = (const float*)d_in[2];
  const float* bq = (const float*)d_in[3];
  const float* wk = (const float*)d_in[4];
  const float* bk = (const float*)d_in[5];
  const float* wv = (const float*)d_in[6];
  const float* bv = (const float*)d_in[7];
  const float* wo = (const float*)d_in[8];
  const float* bo = (const float*)d_in[9];
  const float* ln1_g = (const float*)d_in[10];
  const float* ln1_b = (const float*)d_in[11];
  const float* w1 = (const float*)d_in[12];
  const float* b1 = (const float*)d_in[13];
  const float* w2 = (const float*)d_in[14];
  const float* b2 = (const float*)d_in[15];
  const float* ln2_g = (const float*)d_in[16];
  const float* ln2_b = (const float*)d_in[17];
  const float* lnf_g = (const float*)d_in[18];
  const float* lnf_b = (const float*)d_in[19];
  const float* lm_w = (const float*)d_in[20];

  char* w = (char*)d_ws;
  float* h    = (float*)(w);                      // 8 MB   fp32 residual
  u16*  hn    = (u16*)(w + (8ll << 20));          // 4 MB   bf16 LN out
  u16*  qkvb  = (u16*)(w + (12ll << 20));         // 12 MB  bf16 packed qkv
  u16*  cbuf  = (u16*)(w + (24ll << 20));         // 4 MB   bf16 attn ctx
  u16*  ff    = qkvb;                             // 16 MB  alias qkv+cbuf
  u16*  wqkvT = (u16*)(w + (28ll << 20));         // 36 MB  [L][3072][1024]
  u16*  woT   = (u16*)(w + (64ll << 20));         // 12 MB  [L][1024][1024]
  u16*  w1T   = (u16*)(w + (76ll << 20));         // 48 MB  [L][4096][1024]
  u16*  w2T   = (u16*)(w + (124ll << 20));        // 48 MB  [L][1024][4096]
  u16*  lmT   = (u16*)(w + (172ll << 20));        // 62.5MB [32000][1024]
  float* bqkv = (float*)(w + (235ll << 20));      // 72 KB  [L][3072]

  const size_t DD = (size_t)D_MODEL * D_MODEL;
  const size_t DDF = (size_t)D_MODEL * DF_DIM;
  const long QS = (long)QKV_N * D_MODEL;
  transpose_cvt<<<dim3(32, 32, L_NUM), 256, 0, stream>>>(wq, wqkvT, D_MODEL, D_MODEL, QS);
  transpose_cvt<<<dim3(32, 32, L_NUM), 256, 0, stream>>>(wk, wqkvT + DD, D_MODEL, D_MODEL, QS);
  transpose_cvt<<<dim3(32, 32, L_NUM), 256, 0, stream>>>(wv, wqkvT + 2 * DD, D_MODEL, D_MODEL, QS);
  transpose_cvt<<<dim3(32, 32, L_NUM), 256, 0, stream>>>(wo, woT, D_MODEL, D_MODEL, (long)DD);
  transpose_cvt<<<dim3(128, 32, L_NUM), 256, 0, stream>>>(w1, w1T, D_MODEL, DF_DIM, (long)DDF);
  transpose_cvt<<<dim3(32, 128, L_NUM), 256, 0, stream>>>(w2, w2T, DF_DIM, D_MODEL, (long)DDF);
  transpose_cvt<<<dim3(V_SIZE / 32, 32, 1), 256, 0, stream>>>(lm_w, lmT, D_MODEL, V_SIZE, 0);
  pack_qkv_bias<<<L_NUM * QKV_N / 256, 256, 0, stream>>>(bq, bk, bv, bqkv);

  embed_kernel<<<ROWS, 256, 0, stream>>>(x, tok_emb, h);

  const int nQKV = (ROWS / 128) * (QKV_N / 128);   // 384
  const int nPRJ = (ROWS / 64) * (D_MODEL / 128);  // 256
  const int nFF1 = (ROWS / 128) * (DF_DIM / 128);  // 512
  const int nFF2 = (ROWS / 64) * (D_MODEL / 128);  // 256
  const int nLM  = (ROWS / 128) * (V_SIZE / 128);  // 4000
  for (int l = 0; l < L_NUM; ++l) {
    layernorm_kernel<<<ROWS / 4, 256, 0, stream>>>(h, ln1_g + l * D_MODEL, ln1_b + l * D_MODEL, hn);
    gemm_bf16<128, 0, false><<<nQKV, 256, 0, stream>>>(
        hn, wqkvT + (size_t)l * QS, bqkv + l * QKV_N, nullptr, qkvb,
        ROWS, QKV_N, D_MODEL);
    attn_mfma<<<dim3(S_LEN / QBLK, B_SZ * H_NUM), 256, 0, stream>>>(qkvb, cbuf);
    gemm_bf16<64, 1, false><<<nPRJ, 256, 0, stream>>>(
        cbuf, woT + l * DD, bo + l * D_MODEL, h, nullptr, ROWS, D_MODEL, D_MODEL);
    layernorm_kernel<<<ROWS / 4, 256, 0, stream>>>(h, ln2_g + l * D_MODEL, ln2_b + l * D_MODEL, hn);
    gemm_bf16<128, 0, true><<<nFF1, 256, 0, stream>>>(
        hn, w1T + l * DDF, b1 + l * DF_DIM, nullptr, ff, ROWS, DF_DIM, D_MODEL);
    gemm_bf16<64, 1, false><<<nFF2, 256, 0, stream>>>(
        ff, w2T + l * DDF, b2 + l * D_MODEL, h, nullptr, ROWS, D_MODEL, DF_DIM);
  }
  layernorm_kernel<<<ROWS / 4, 256, 0, stream>>>(h, lnf_g, lnf_b, hn);
  gemm_bf16<128, 2, false><<<nLM, 256, 0, stream>>>(
      hn, lmT, nullptr, (float*)d_out, nullptr, ROWS, V_SIZE, D_MODEL);
}

// Round 5
// 1768.612 us; speedup vs baseline: 6.5671x; 1.0558x over previous
//
#include <hip/hip_runtime.h>
#include <hip/hip_bf16.h>
#include <math.h>

// GPT forward. V=32000 L=6 H=16 D=1024 S=512 B=4, DK=64, DF=4096.
// Round 4: 256^2 8-phase counted-vmcnt GEMM for LM head; attn setprio;
// faster transpose prep.
#define V_SIZE 32000
#define L_NUM 6
#define H_NUM 16
#define D_MODEL 1024
#define S_LEN 512
#define B_SZ 4
#define DF_DIM 4096
#define ROWS (B_SZ * S_LEN)   // 2048
#define QKV_N (3 * D_MODEL)   // 3072
#define QBLK 128
#define KVBLK 64

typedef unsigned short u16;
typedef __attribute__((ext_vector_type(8))) short short8v;   // 8 bf16
typedef __attribute__((ext_vector_type(4))) float f32x4;

__device__ __forceinline__ float b2f(u16 b) {
  union { float f; unsigned u; } c; c.u = ((unsigned)b) << 16; return c.f;
}
__device__ __forceinline__ u16 f2b(float f) {
  __hip_bfloat16 h = __float2bfloat16(f);
  union { __hip_bfloat16 h; u16 u; } c; c.h = h; return c.u;
}
__device__ __forceinline__ void g2l16(const void* g, void* l) {
  __builtin_amdgcn_global_load_lds(
      (const __attribute__((address_space(1))) void*)g,
      (__attribute__((address_space(3))) void*)l, 16, 0, 0);
}

// ---------------- embedding + sinusoidal PE (fp32 out) ----------------
__global__ __launch_bounds__(256) void embed_kernel(
    const int* __restrict__ x, const float* __restrict__ tok_emb,
    float* __restrict__ h) {
  int row = blockIdx.x;
  int s = row % S_LEN;
  int tok = x[row];
  const float* te = tok_emb + (size_t)tok * D_MODEL;
  float* hr = h + (size_t)row * D_MODEL;
  float pos = (float)s;
  const float c = 9.210340371976184f / (float)D_MODEL;  // ln(10000)/D
#pragma unroll
  for (int i = 0; i < D_MODEL / 256; ++i) {
    int d = threadIdx.x + i * 256;
    float freq = expf(-(float)(d & ~1) * c);
    float ang = pos * freq;
    float pe = (d & 1) ? cosf(ang) : sinf(ang);
    hr[d] = te[d] + pe;
  }
}

// ---------------- layernorm: wave per row, float4 loads, bf16 out ----------------
__global__ __launch_bounds__(256) void layernorm_kernel(
    const float* __restrict__ in, const float* __restrict__ g,
    const float* __restrict__ b, u16* __restrict__ out) {
  const int row = blockIdx.x * 4 + (threadIdx.x >> 6);
  const int lane = threadIdx.x & 63;
  const float4* xr = (const float4*)(in + (size_t)row * D_MODEL);
  float4 v[4];
  float s1 = 0.f, s2 = 0.f;
#pragma unroll
  for (int i = 0; i < 4; ++i) {
    float4 t = xr[lane + i * 64];
    v[i] = t;
    s1 += t.x + t.y + t.z + t.w;
    s2 += t.x * t.x + t.y * t.y + t.z * t.z + t.w * t.w;
  }
#pragma unroll
  for (int off = 32; off; off >>= 1) {
    s1 += __shfl_xor(s1, off, 64);
    s2 += __shfl_xor(s2, off, 64);
  }
  const float mu = s1 * (1.0f / D_MODEL);
  const float var = s2 * (1.0f / D_MODEL) - mu * mu;
  const float rstd = rsqrtf(var + 1e-5f);
  u16* orow = out + (size_t)row * D_MODEL;
#pragma unroll
  for (int i = 0; i < 4; ++i) {
    const int d = (lane + i * 64) * 4;
    const float4 gv = *(const float4*)&g[d];
    const float4 bv = *(const float4*)&b[d];
    u16 o0 = f2b((v[i].x - mu) * rstd * gv.x + bv.x);
    u16 o1 = f2b((v[i].y - mu) * rstd * gv.y + bv.y);
    u16 o2 = f2b((v[i].z - mu) * rstd * gv.z + bv.z);
    u16 o3 = f2b((v[i].w - mu) * rstd * gv.w + bv.w);
    uint2 pk;
    pk.x = (unsigned)o0 | ((unsigned)o1 << 16);
    pk.y = (unsigned)o2 | ((unsigned)o3 << 16);
    *(uint2*)&orow[d] = pk;
  }
}

// ---------------- fp32 [K][N] -> bf16 [N][K] transpose (batched over z) ----------------
// 64(k) x 32(n) tile; packed uint stores (full-rate writes).
__global__ __launch_bounds__(256) void transpose_cvt(
    const float* __restrict__ W, u16* __restrict__ Wt, int K, int N,
    long out_stride) {
  __shared__ float t[64][33];
  const float* Wl = W + (size_t)blockIdx.z * K * N;
  u16* Wtl = Wt + (size_t)blockIdx.z * out_stride;
  const int n0 = blockIdx.x * 32, k0 = blockIdx.y * 64;
  const int tx = threadIdx.x & 31, ty = threadIdx.x >> 5;   // ty 0..7
#pragma unroll
  for (int i = 0; i < 64; i += 8)
    t[ty + i][tx] = Wl[(size_t)(k0 + ty + i) * N + n0 + tx];
  __syncthreads();
#pragma unroll
  for (int j = 0; j < 32; j += 8) {
    const int n = ty + j;
    u16 lo = f2b(t[2 * tx][n]);
    u16 hi = f2b(t[2 * tx + 1][n]);
    *(unsigned*)&Wtl[(size_t)(n0 + n) * K + k0 + 2 * tx] =
        (unsigned)lo | ((unsigned)hi << 16);
  }
}

// ---------------- pack bq|bk|bv -> [L][3072] ----------------
__global__ __launch_bounds__(256) void pack_qkv_bias(
    const float* __restrict__ bq, const float* __restrict__ bk,
    const float* __restrict__ bv, float* __restrict__ out) {
  int i = blockIdx.x * 256 + threadIdx.x;   // 0 .. L*3072-1
  int l = i / QKV_N, j = i % QKV_N;
  float v = (j < D_MODEL) ? bq[l * D_MODEL + j]
          : (j < 2 * D_MODEL) ? bk[l * D_MODEL + j - D_MODEL]
          : bv[l * D_MODEL + j - 2 * D_MODEL];
  out[i] = v;
}

// ---------------- bf16 MFMA GEMM (m97 128^2): C = A @ Bt^T ----------------
template <int TM, int OUT_MODE, bool GELU_ACT>
__global__ __launch_bounds__(256) void gemm_bf16(
    const u16* __restrict__ A, const u16* __restrict__ Bt,
    const float* __restrict__ bias, float* __restrict__ Cf,
    u16* __restrict__ Cb, int M, int N, int K) {
  constexpr int MF = TM / 32;
  constexpr int ALOADS = TM / 64;
  __shared__ __align__(16) u16 As[TM * 32];
  __shared__ __align__(16) u16 Bs[128 * 32];
  const int tid = threadIdx.x;
  const int wid = tid >> 6;
  const int lane = tid & 63;
  const int wr = wid >> 1, wc = wid & 1;
  const int nwg = gridDim.x;
  const int id = blockIdx.x;
  const int q = nwg >> 3, r = nwg & 7;
  const int xcd = id & 7, i0 = id >> 3;
  const int swz = (xcd < r ? xcd * (q + 1) : r * (q + 1) + (xcd - r) * q) + i0;
  const int gm = M / TM;
  const int bm = swz % gm, bn = swz / gm;
  const u16* Ag = A + (size_t)(bm * TM + wid * (TM / 4) + (lane >> 2)) * K + (lane & 3) * 8;
  const u16* Bg = Bt + (size_t)(bn * 128 + wid * 32 + (lane >> 2)) * K + (lane & 3) * 8;
  u16* Asw = As + wid * (TM / 4) * 32;
  u16* Bsw = Bs + wid * 1024;
  f32x4 acc[MF][4] = {};
  const int fr = lane & 15;
  const int ko = (lane >> 4) * 8;
  for (int k0 = 0; k0 < K; k0 += 32) {
#pragma unroll
    for (int i = 0; i < ALOADS; ++i)
      g2l16(Ag + k0 + (size_t)(16 * i) * K, Asw + 512 * i);
    g2l16(Bg + k0, Bsw);
    g2l16(Bg + k0 + (size_t)16 * K, Bsw + 512);
    __syncthreads();
    short8v a[MF], b[4];
#pragma unroll
    for (int m = 0; m < MF; ++m)
      a[m] = *(const short8v*)&As[(wr * (TM / 2) + m * 16 + fr) * 32 + ko];
#pragma unroll
    for (int n = 0; n < 4; ++n)
      b[n] = *(const short8v*)&Bs[(wc * 64 + n * 16 + fr) * 32 + ko];
#pragma unroll
    for (int m = 0; m < MF; ++m)
#pragma unroll
      for (int n = 0; n < 4; ++n)
        acc[m][n] = __builtin_amdgcn_mfma_f32_16x16x32_bf16(a[m], b[n], acc[m][n], 0, 0, 0);
    __syncthreads();
  }
  const int row0 = bm * TM + wr * (TM / 2) + (lane >> 4) * 4;
  const int col0 = bn * 128 + wc * 64 + fr;
#pragma unroll
  for (int m = 0; m < MF; ++m) {
#pragma unroll
    for (int n = 0; n < 4; ++n) {
      const int col = col0 + n * 16;
      float bv = (OUT_MODE == 2) ? 0.f : bias[col];
#pragma unroll
      for (int r2 = 0; r2 < 4; ++r2) {
        const int row = row0 + m * 16 + r2;
        float v = acc[m][n][r2] + bv;
        if (GELU_ACT) v = 0.5f * v * (1.0f + erff(v * 0.70710678118f));
        size_t idx = (size_t)row * N + col;
        if (OUT_MODE == 0) Cb[idx] = f2b(v);
        else if (OUT_MODE == 1) Cf[idx] += v;
        else Cf[idx] = v;
      }
    }
  }
}

// ---------------- 256^2 8-phase counted-vmcnt GEMM (LM head) ----------------
// C[M,N] fp32 = A[M,K]bf16 @ Bt[N,K]^T bf16.  512 thr = 8 waves (2M x 4N).
// LDS 128 KiB: A[2][256][64] | B[2][256][64], group-XOR swizzled (g ^= row&7)
// with pre-swizzled global source (linear global_load_lds dest).
// Per K-tile: 4 quadrant phases; stages target provably-dead regions:
//   p0: B-Q0,Q1(t+1)->nxt   p1: B-Q2,Q3(t+1)->nxt   p2: A-Q1,Q3(t+1)->nxt
//   p3: A-Q0,Q2(t+2)->cur   [A-even of cur dead after p1]
// Boundary wait: vmcnt(2) (the 2 p3-stages), vmcnt(0) at tail. Never drains
// mid-pipeline.
__global__ __launch_bounds__(512, 2) void gemm256_lm(
    const u16* __restrict__ A, const u16* __restrict__ Bt,
    float* __restrict__ C, int M, int N, int K) {
  extern __shared__ __align__(16) u16 smem[];   // 128 KiB
  const int tid = threadIdx.x, wid = tid >> 6, lane = tid & 63;
  const int wm = wid >> 2, wn = wid & 3;
  const int fr = lane & 15, hi = lane >> 4;
  const int T = K / 64;
  const int nwg = gridDim.x, id = blockIdx.x;
  const int q = nwg >> 3, r = nwg & 7;
  const int xcd = id & 7, i0 = id >> 3;
  const int swz = (xcd < r ? xcd * (q + 1) : r * (q + 1) + (xcd - r) * q) + i0;
  const int gm = M / 256;
  const int bm = swz % gm, bn = swz / gm;
  const int rowA0 = bm * 256, rowB0 = bn * 256;
  const int rowoff = wid * 8 + (lane >> 3);
  const int gsw = ((lane & 7) ^ (lane >> 3)) * 8;   // pre-swizzled source group
  auto stA = [&](int qq, int tt, int bb) {
    g2l16(A + (size_t)(rowA0 + qq * 64 + rowoff) * K + tt * 64 + gsw,
          smem + bb * 16384 + qq * 4096 + wid * 512);
  };
  auto stB = [&](int qq, int tt, int bb) {
    g2l16(Bt + (size_t)(rowB0 + qq * 64 + rowoff) * K + tt * 64 + gsw,
          smem + 32768 + bb * 16384 + qq * 4096 + wid * 512);
  };
  f32x4 acc[8][4] = {};
  // prologue: tile0 fully + A-even of tile1; leave the last 2 in flight
  stA(0, 0, 0); stA(2, 0, 0);
  stB(0, 0, 0); stB(1, 0, 0); stB(2, 0, 0); stB(3, 0, 0);
  stA(1, 0, 0); stA(3, 0, 0);
  if (T > 1) {
    stA(0, 1, 1); stA(2, 1, 1);
    asm volatile("s_waitcnt vmcnt(2)" ::: "memory");
  } else {
    asm volatile("s_waitcnt vmcnt(0)" ::: "memory");
  }
  __builtin_amdgcn_s_barrier();
  for (int t = 0; t < T; ++t) {
    const int cur = t & 1, nxt = cur ^ 1;
#pragma unroll
    for (int p = 0; p < 4; ++p) {
      short8v a[4][2], b[2][2];
#pragma unroll
      for (int m = 0; m < 4; ++m)
#pragma unroll
        for (int ks = 0; ks < 2; ++ks) {
          const int row = wm * 128 + (p >> 1) * 64 + m * 16 + fr;
          const int g = (ks * 4 + hi) ^ (fr & 7);
          a[m][ks] = *(const short8v*)&smem[cur * 16384 + row * 64 + g * 8];
        }
#pragma unroll
      for (int n = 0; n < 2; ++n)
#pragma unroll
        for (int ks = 0; ks < 2; ++ks) {
          const int row = wn * 64 + (p & 1) * 32 + n * 16 + fr;
          const int g = (ks * 4 + hi) ^ (fr & 7);
          b[n][ks] = *(const short8v*)&smem[32768 + cur * 16384 + row * 64 + g * 8];
        }
      if (p == 0 && t + 1 < T) { stB(0, t + 1, nxt); stB(1, t + 1, nxt); }
      if (p == 1 && t + 1 < T) { stB(2, t + 1, nxt); stB(3, t + 1, nxt); }
      if (p == 2 && t + 1 < T) { stA(1, t + 1, nxt); stA(3, t + 1, nxt); }
      if (p == 3 && t + 2 < T) { stA(0, t + 2, cur); stA(2, t + 2, cur); }
      __builtin_amdgcn_s_barrier();
      asm volatile("s_waitcnt lgkmcnt(0)" ::: "memory");
      __builtin_amdgcn_sched_barrier(0);
      __builtin_amdgcn_s_setprio(1);
#pragma unroll
      for (int ks = 0; ks < 2; ++ks)
#pragma unroll
        for (int m = 0; m < 4; ++m)
#pragma unroll
          for (int n = 0; n < 2; ++n)
            acc[(p >> 1) * 4 + m][(p & 1) * 2 + n] =
                __builtin_amdgcn_mfma_f32_16x16x32_bf16(
                    a[m][ks], b[n][ks],
                    acc[(p >> 1) * 4 + m][(p & 1) * 2 + n], 0, 0, 0);
      __builtin_amdgcn_s_setprio(0);
      if (p == 3) {
        if (t + 1 < T) {   // boundary: tile t+1 data must be resident
          if (t + 2 < T) asm volatile("s_waitcnt vmcnt(2)" ::: "memory");
          else           asm volatile("s_waitcnt vmcnt(0)" ::: "memory");
          __builtin_amdgcn_s_barrier();
        }
      } else {
        __builtin_amdgcn_s_barrier();
      }
    }
  }
  const int r0 = rowA0 + wm * 128 + hi * 4;
  const int c0 = rowB0 + wn * 64 + fr;
#pragma unroll
  for (int m = 0; m < 8; ++m)
#pragma unroll
    for (int n = 0; n < 4; ++n)
#pragma unroll
      for (int rr = 0; rr < 4; ++rr)
        C[(size_t)(r0 + m * 16 + rr) * N + c0 + n * 16] = acc[m][n][rr];
}

// ---------------- flash-style MFMA attention ----------------
__global__ __launch_bounds__(256) void attn_mfma(
    const u16* __restrict__ qkv, u16* __restrict__ ctx) {
  __shared__ __align__(16) u16 smem[18432];
  u16 (*Qs)[72] = (u16(*)[72])smem;             // [128][72]
  u16 (*Ks)[72] = (u16(*)[72])(smem + 9216);    // [64][72]
  u16 (*Vs)[72] = (u16(*)[72])(smem + 13824);   // [64][72]  V^T: [d][k]
  const int qt = blockIdx.x, bh = blockIdx.y;
  const int b = bh >> 4, h = bh & 15;
  const int tid = threadIdx.x, wid = tid >> 6, lane = tid & 63;
  const int fr = lane & 15, ko = (lane >> 4) * 8;
  u16 (*Ps)[72] = (u16(*)[72])(smem + wid * 2304);  // [32][72]/wave, aliases Qs
  const size_t rb = (size_t)b * S_LEN;
  const int q0 = qt * QBLK;
  const int hq = h * 64;
#pragma unroll
  for (int i = 0; i < 4; ++i) {
    int e = tid + i * 256, r = e >> 3, c = (e & 7) * 8;
    *(short8v*)&Qs[r][c] = *(const short8v*)&qkv[(rb + q0 + r) * QKV_N + hq + c];
  }
  __syncthreads();
  short8v qf[2][2];
#pragma unroll
  for (int m = 0; m < 2; ++m)
#pragma unroll
    for (int ks = 0; ks < 2; ++ks)
      qf[m][ks] = *(const short8v*)&Qs[wid * 32 + m * 16 + fr][ks * 32 + ko];
  f32x4 acc_o[2][4] = {};
  float mrow[2][4], lrow[2][4];
#pragma unroll
  for (int m = 0; m < 2; ++m)
#pragma unroll
    for (int r = 0; r < 4; ++r) { mrow[m][r] = -1e30f; lrow[m][r] = 0.f; }
  const int nt = 2 * qt + 2;
  for (int t = 0; t < nt; ++t) {
    const int k0 = t * KVBLK;
    __syncthreads();
#pragma unroll
    for (int i = 0; i < 2; ++i) {
      int e = tid + i * 256, r = e >> 3, c = (e & 7) * 8;
      *(short8v*)&Ks[r][c] =
          *(const short8v*)&qkv[(rb + k0 + r) * QKV_N + D_MODEL + hq + c];
      short8v vv = *(const short8v*)&qkv[(rb + k0 + r) * QKV_N + 2 * D_MODEL + hq + c];
#pragma unroll
      for (int j = 0; j < 8; ++j) Vs[c + j][r] = (u16)vv[j];
    }
    __syncthreads();
    f32x4 s[2][4] = {};
    __builtin_amdgcn_s_setprio(1);
#pragma unroll
    for (int n = 0; n < 4; ++n)
#pragma unroll
      for (int ks = 0; ks < 2; ++ks) {
        short8v kf = *(const short8v*)&Ks[n * 16 + fr][ks * 32 + ko];
#pragma unroll
        for (int m = 0; m < 2; ++m)
          s[m][n] = __builtin_amdgcn_mfma_f32_16x16x32_bf16(qf[m][ks], kf, s[m][n], 0, 0, 0);
      }
    __builtin_amdgcn_s_setprio(0);
#pragma unroll
    for (int m = 0; m < 2; ++m) {
      const int rbase = q0 + wid * 32 + m * 16 + (lane >> 4) * 4;
#pragma unroll
      for (int r = 0; r < 4; ++r) {
        const int row_g = rbase + r;
        float vmax = -1e30f;
#pragma unroll
        for (int n = 0; n < 4; ++n) {
          float v = s[m][n][r] * 0.125f;
          if (k0 + n * 16 + fr > row_g) v = -1e30f;
          s[m][n][r] = v;
          vmax = fmaxf(vmax, v);
        }
#pragma unroll
        for (int off = 1; off < 16; off <<= 1) vmax = fmaxf(vmax, __shfl_xor(vmax, off, 64));
        const float mnew = fmaxf(mrow[m][r], vmax);
        const float sc = expf(mrow[m][r] - mnew);
        mrow[m][r] = mnew;
        float ssum = 0.f;
#pragma unroll
        for (int n = 0; n < 4; ++n) {
          float p = expf(s[m][n][r] - mnew);
          s[m][n][r] = p;
          ssum += p;
        }
#pragma unroll
        for (int off = 1; off < 16; off <<= 1) ssum += __shfl_xor(ssum, off, 64);
        lrow[m][r] = lrow[m][r] * sc + ssum;
#pragma unroll
        for (int n = 0; n < 4; ++n) {
          acc_o[m][n][r] *= sc;
          Ps[m * 16 + (lane >> 4) * 4 + r][n * 16 + fr] = f2b(s[m][n][r]);
        }
      }
    }
    __builtin_amdgcn_s_setprio(1);
#pragma unroll
    for (int ks = 0; ks < 2; ++ks) {
      short8v pf[2];
#pragma unroll
      for (int m = 0; m < 2; ++m) pf[m] = *(const short8v*)&Ps[m * 16 + fr][ks * 32 + ko];
#pragma unroll
      for (int n = 0; n < 4; ++n) {
        short8v vf = *(const short8v*)&Vs[n * 16 + fr][ks * 32 + ko];
#pragma unroll
        for (int m = 0; m < 2; ++m)
          acc_o[m][n] = __builtin_amdgcn_mfma_f32_16x16x32_bf16(pf[m], vf, acc_o[m][n], 0, 0, 0);
      }
    }
    __builtin_amdgcn_s_setprio(0);
  }
#pragma unroll
  for (int m = 0; m < 2; ++m)
#pragma unroll
    for (int r = 0; r < 4; ++r) {
      const int row_g = q0 + wid * 32 + m * 16 + (lane >> 4) * 4 + r;
      const float inv = 1.0f / lrow[m][r];
#pragma unroll
      for (int n = 0; n < 4; ++n)
        ctx[(rb + row_g) * D_MODEL + hq + n * 16 + fr] = f2b(acc_o[m][n][r] * inv);
    }
}

// ---------------- launch ----------------
extern "C" void kernel_launch(void* const* d_in, const int* in_sizes, int n_in,
                              void* d_out, int out_size, void* d_ws, size_t ws_size,
                              hipStream_t stream) {
  const int* x = (const int*)d_in[0];
  const float* tok_emb = (const float*)d_in[1];
  const float* wq = (const float*)d_in[2];
  const float* bq = (const float*)d_in[3];
  const float* wk = (const float*)d_in[4];
  const float* bk = (const float*)d_in[5];
  const float* wv = (const float*)d_in[6];
  const float* bv = (const float*)d_in[7];
  const float* wo = (const float*)d_in[8];
  const float* bo = (const float*)d_in[9];
  const float* ln1_g = (const float*)d_in[10];
  const float* ln1_b = (const float*)d_in[11];
  const float* w1 = (const float*)d_in[12];
  const float* b1 = (const float*)d_in[13];
  const float* w2 = (const float*)d_in[14];
  const float* b2 = (const float*)d_in[15];
  const float* ln2_g = (const float*)d_in[16];
  const float* ln2_b = (const float*)d_in[17];
  const float* lnf_g = (const float*)d_in[18];
  const float* lnf_b = (const float*)d_in[19];
  const float* lm_w = (const float*)d_in[20];

  char* w = (char*)d_ws;
  float* h    = (float*)(w);                      // 8 MB   fp32 residual
  u16*  hn    = (u16*)(w + (8ll << 20));          // 4 MB   bf16 LN out
  u16*  qkvb  = (u16*)(w + (12ll << 20));         // 12 MB  bf16 packed qkv
  u16*  cbuf  = (u16*)(w + (24ll << 20));         // 4 MB   bf16 attn ctx
  u16*  ff    = qkvb;                             // 16 MB  alias qkv+cbuf
  u16*  wqkvT = (u16*)(w + (28ll << 20));         // 36 MB  [L][3072][1024]
  u16*  woT   = (u16*)(w + (64ll << 20));         // 12 MB  [L][1024][1024]
  u16*  w1T   = (u16*)(w + (76ll << 20));         // 48 MB  [L][4096][1024]
  u16*  w2T   = (u16*)(w + (124ll << 20));        // 48 MB  [L][1024][4096]
  u16*  lmT   = (u16*)(w + (172ll << 20));        // 62.5MB [32000][1024]
  float* bqkv = (float*)(w + (235ll << 20));      // 72 KB  [L][3072]

  const size_t DD = (size_t)D_MODEL * D_MODEL;
  const size_t DDF = (size_t)D_MODEL * DF_DIM;
  const long QS = (long)QKV_N * D_MODEL;
  transpose_cvt<<<dim3(32, 16, L_NUM), 256, 0, stream>>>(wq, wqkvT, D_MODEL, D_MODEL, QS);
  transpose_cvt<<<dim3(32, 16, L_NUM), 256, 0, stream>>>(wk, wqkvT + DD, D_MODEL, D_MODEL, QS);
  transpose_cvt<<<dim3(32, 16, L_NUM), 256, 0, stream>>>(wv, wqkvT + 2 * DD, D_MODEL, D_MODEL, QS);
  transpose_cvt<<<dim3(32, 16, L_NUM), 256, 0, stream>>>(wo, woT, D_MODEL, D_MODEL, (long)DD);
  transpose_cvt<<<dim3(128, 16, L_NUM), 256, 0, stream>>>(w1, w1T, D_MODEL, DF_DIM, (long)DDF);
  transpose_cvt<<<dim3(32, 64, L_NUM), 256, 0, stream>>>(w2, w2T, DF_DIM, D_MODEL, (long)DDF);
  transpose_cvt<<<dim3(V_SIZE / 32, 16, 1), 256, 0, stream>>>(lm_w, lmT, D_MODEL, V_SIZE, 0);
  pack_qkv_bias<<<L_NUM * QKV_N / 256, 256, 0, stream>>>(bq, bk, bv, bqkv);

  embed_kernel<<<ROWS, 256, 0, stream>>>(x, tok_emb, h);

  const int nQKV = (ROWS / 128) * (QKV_N / 128);   // 384
  const int nPRJ = (ROWS / 64) * (D_MODEL / 128);  // 256
  const int nFF1 = (ROWS / 128) * (DF_DIM / 128);  // 512
  const int nFF2 = (ROWS / 64) * (D_MODEL / 128);  // 256
  for (int l = 0; l < L_NUM; ++l) {
    layernorm_kernel<<<ROWS / 4, 256, 0, stream>>>(h, ln1_g + l * D_MODEL, ln1_b + l * D_MODEL, hn);
    gemm_bf16<128, 0, false><<<nQKV, 256, 0, stream>>>(
        hn, wqkvT + (size_t)l * QS, bqkv + l * QKV_N, nullptr, qkvb,
        ROWS, QKV_N, D_MODEL);
    attn_mfma<<<dim3(S_LEN / QBLK, B_SZ * H_NUM), 256, 0, stream>>>(qkvb, cbuf);
    gemm_bf16<64, 1, false><<<nPRJ, 256, 0, stream>>>(
        cbuf, woT + l * DD, bo + l * D_MODEL, h, nullptr, ROWS, D_MODEL, D_MODEL);
    layernorm_kernel<<<ROWS / 4, 256, 0, stream>>>(h, ln2_g + l * D_MODEL, ln2_b + l * D_MODEL, hn);
    gemm_bf16<128, 0, true><<<nFF1, 256, 0, stream>>>(
        hn, w1T + l * DDF, b1 + l * DF_DIM, nullptr, ff, ROWS, DF_DIM, D_MODEL);
    gemm_bf16<64, 1, false><<<nFF2, 256, 0, stream>>>(
        ff, w2T + l * DDF, b2 + l * D_MODEL, h, nullptr, ROWS, D_MODEL, DF_DIM);
  }
  layernorm_kernel<<<ROWS / 4, 256, 0, stream>>>(h, lnf_g, lnf_b, hn);

  hipFuncSetAttribute((const void*)gemm256_lm,
                      hipFuncAttributeMaxDynamicSharedMemorySize, 131072);
  const int nLM = (ROWS / 256) * (V_SIZE / 256);   // 8 * 125 = 1000
  gemm256_lm<<<nLM, 512, 131072, stream>>>(
      hn, lmT, (float*)d_out, ROWS, V_SIZE, D_MODEL);
}

// Round 6
// 1692.793 us; speedup vs baseline: 6.8612x; 1.0448x over previous
//
#include <hip/hip_runtime.h>
#include <hip/hip_bf16.h>
#include <math.h>

// GPT forward. V=32000 L=6 H=16 D=1024 S=512 B=4, DK=64, DF=4096.
// Round 5: LM-head coalesced LDS-staged epilogue; 2-phase prefetch (dbuf)
// for layer GEMMs.
#define V_SIZE 32000
#define L_NUM 6
#define H_NUM 16
#define D_MODEL 1024
#define S_LEN 512
#define B_SZ 4
#define DF_DIM 4096
#define ROWS (B_SZ * S_LEN)   // 2048
#define QKV_N (3 * D_MODEL)   // 3072
#define QBLK 128
#define KVBLK 64

typedef unsigned short u16;
typedef __attribute__((ext_vector_type(8))) short short8v;   // 8 bf16
typedef __attribute__((ext_vector_type(4))) float f32x4;

__device__ __forceinline__ float b2f(u16 b) {
  union { float f; unsigned u; } c; c.u = ((unsigned)b) << 16; return c.f;
}
__device__ __forceinline__ u16 f2b(float f) {
  __hip_bfloat16 h = __float2bfloat16(f);
  union { __hip_bfloat16 h; u16 u; } c; c.h = h; return c.u;
}
__device__ __forceinline__ void g2l16(const void* g, void* l) {
  __builtin_amdgcn_global_load_lds(
      (const __attribute__((address_space(1))) void*)g,
      (__attribute__((address_space(3))) void*)l, 16, 0, 0);
}

// ---------------- embedding + sinusoidal PE (fp32 out) ----------------
__global__ __launch_bounds__(256) void embed_kernel(
    const int* __restrict__ x, const float* __restrict__ tok_emb,
    float* __restrict__ h) {
  int row = blockIdx.x;
  int s = row % S_LEN;
  int tok = x[row];
  const float* te = tok_emb + (size_t)tok * D_MODEL;
  float* hr = h + (size_t)row * D_MODEL;
  float pos = (float)s;
  const float c = 9.210340371976184f / (float)D_MODEL;  // ln(10000)/D
#pragma unroll
  for (int i = 0; i < D_MODEL / 256; ++i) {
    int d = threadIdx.x + i * 256;
    float freq = expf(-(float)(d & ~1) * c);
    float ang = pos * freq;
    float pe = (d & 1) ? cosf(ang) : sinf(ang);
    hr[d] = te[d] + pe;
  }
}

// ---------------- layernorm: wave per row, float4 loads, bf16 out ----------------
__global__ __launch_bounds__(256) void layernorm_kernel(
    const float* __restrict__ in, const float* __restrict__ g,
    const float* __restrict__ b, u16* __restrict__ out) {
  const int row = blockIdx.x * 4 + (threadIdx.x >> 6);
  const int lane = threadIdx.x & 63;
  const float4* xr = (const float4*)(in + (size_t)row * D_MODEL);
  float4 v[4];
  float s1 = 0.f, s2 = 0.f;
#pragma unroll
  for (int i = 0; i < 4; ++i) {
    float4 t = xr[lane + i * 64];
    v[i] = t;
    s1 += t.x + t.y + t.z + t.w;
    s2 += t.x * t.x + t.y * t.y + t.z * t.z + t.w * t.w;
  }
#pragma unroll
  for (int off = 32; off; off >>= 1) {
    s1 += __shfl_xor(s1, off, 64);
    s2 += __shfl_xor(s2, off, 64);
  }
  const float mu = s1 * (1.0f / D_MODEL);
  const float var = s2 * (1.0f / D_MODEL) - mu * mu;
  const float rstd = rsqrtf(var + 1e-5f);
  u16* orow = out + (size_t)row * D_MODEL;
#pragma unroll
  for (int i = 0; i < 4; ++i) {
    const int d = (lane + i * 64) * 4;
    const float4 gv = *(const float4*)&g[d];
    const float4 bv = *(const float4*)&b[d];
    u16 o0 = f2b((v[i].x - mu) * rstd * gv.x + bv.x);
    u16 o1 = f2b((v[i].y - mu) * rstd * gv.y + bv.y);
    u16 o2 = f2b((v[i].z - mu) * rstd * gv.z + bv.z);
    u16 o3 = f2b((v[i].w - mu) * rstd * gv.w + bv.w);
    uint2 pk;
    pk.x = (unsigned)o0 | ((unsigned)o1 << 16);
    pk.y = (unsigned)o2 | ((unsigned)o3 << 16);
    *(uint2*)&orow[d] = pk;
  }
}

// ---------------- fp32 [K][N] -> bf16 [N][K] transpose (batched over z) ----------------
__global__ __launch_bounds__(256) void transpose_cvt(
    const float* __restrict__ W, u16* __restrict__ Wt, int K, int N,
    long out_stride) {
  __shared__ float t[64][33];
  const float* Wl = W + (size_t)blockIdx.z * K * N;
  u16* Wtl = Wt + (size_t)blockIdx.z * out_stride;
  const int n0 = blockIdx.x * 32, k0 = blockIdx.y * 64;
  const int tx = threadIdx.x & 31, ty = threadIdx.x >> 5;   // ty 0..7
#pragma unroll
  for (int i = 0; i < 64; i += 8)
    t[ty + i][tx] = Wl[(size_t)(k0 + ty + i) * N + n0 + tx];
  __syncthreads();
#pragma unroll
  for (int j = 0; j < 32; j += 8) {
    const int n = ty + j;
    u16 lo = f2b(t[2 * tx][n]);
    u16 hi = f2b(t[2 * tx + 1][n]);
    *(unsigned*)&Wtl[(size_t)(n0 + n) * K + k0 + 2 * tx] =
        (unsigned)lo | ((unsigned)hi << 16);
  }
}

// ---------------- pack bq|bk|bv -> [L][3072] ----------------
__global__ __launch_bounds__(256) void pack_qkv_bias(
    const float* __restrict__ bq, const float* __restrict__ bk,
    const float* __restrict__ bv, float* __restrict__ out) {
  int i = blockIdx.x * 256 + threadIdx.x;   // 0 .. L*3072-1
  int l = i / QKV_N, j = i % QKV_N;
  float v = (j < D_MODEL) ? bq[l * D_MODEL + j]
          : (j < 2 * D_MODEL) ? bk[l * D_MODEL + j - D_MODEL]
          : bv[l * D_MODEL + j - 2 * D_MODEL];
  out[i] = v;
}

// ---------------- bf16 MFMA GEMM (2-phase prefetch): C = A @ Bt^T ----------------
// TM x 128 tile, 256 thr = 4 waves (2x2). Double-buffered LDS; stage(t+1)
// issued before compute(t); single __syncthreads (vmcnt0 drain) per K-step.
template <int TM, int OUT_MODE, bool GELU_ACT>
__global__ __launch_bounds__(256) void gemm_bf16(
    const u16* __restrict__ A, const u16* __restrict__ Bt,
    const float* __restrict__ bias, float* __restrict__ Cf,
    u16* __restrict__ Cb, int M, int N, int K) {
  constexpr int MF = TM / 32;
  constexpr int ALOADS = TM / 64;
  __shared__ __align__(16) u16 As[2][TM * 32];
  __shared__ __align__(16) u16 Bs[2][128 * 32];
  const int tid = threadIdx.x;
  const int wid = tid >> 6;
  const int lane = tid & 63;
  const int wr = wid >> 1, wc = wid & 1;
  const int nwg = gridDim.x;
  const int id = blockIdx.x;
  const int q = nwg >> 3, r = nwg & 7;
  const int xcd = id & 7, i0 = id >> 3;
  const int swz = (xcd < r ? xcd * (q + 1) : r * (q + 1) + (xcd - r) * q) + i0;
  const int gm = M / TM;
  const int bm = swz % gm, bn = swz / gm;
  const u16* Ag = A + (size_t)(bm * TM + wid * (TM / 4) + (lane >> 2)) * K + (lane & 3) * 8;
  const u16* Bg = Bt + (size_t)(bn * 128 + wid * 32 + (lane >> 2)) * K + (lane & 3) * 8;
  auto stage = [&](int buf, int k0) {
#pragma unroll
    for (int i = 0; i < ALOADS; ++i)
      g2l16(Ag + k0 + (size_t)(16 * i) * K, As[buf] + wid * (TM / 4) * 32 + 512 * i);
    g2l16(Bg + k0, Bs[buf] + wid * 1024);
    g2l16(Bg + k0 + (size_t)16 * K, Bs[buf] + wid * 1024 + 512);
  };
  f32x4 acc[MF][4] = {};
  const int fr = lane & 15;
  const int ko = (lane >> 4) * 8;
  stage(0, 0);
  __syncthreads();
  for (int k0 = 0; k0 < K; k0 += 32) {
    const int cur = (k0 >> 5) & 1;
    if (k0 + 32 < K) stage(cur ^ 1, k0 + 32);
    short8v a[MF], b[4];
#pragma unroll
    for (int m = 0; m < MF; ++m)
      a[m] = *(const short8v*)&As[cur][(wr * (TM / 2) + m * 16 + fr) * 32 + ko];
#pragma unroll
    for (int n = 0; n < 4; ++n)
      b[n] = *(const short8v*)&Bs[cur][(wc * 64 + n * 16 + fr) * 32 + ko];
#pragma unroll
    for (int m = 0; m < MF; ++m)
#pragma unroll
      for (int n = 0; n < 4; ++n)
        acc[m][n] = __builtin_amdgcn_mfma_f32_16x16x32_bf16(a[m], b[n], acc[m][n], 0, 0, 0);
    __syncthreads();   // drains next-tile stage (vmcnt0) + barrier
  }
  const int row0 = bm * TM + wr * (TM / 2) + (lane >> 4) * 4;
  const int col0 = bn * 128 + wc * 64 + fr;
#pragma unroll
  for (int m = 0; m < MF; ++m) {
#pragma unroll
    for (int n = 0; n < 4; ++n) {
      const int col = col0 + n * 16;
      float bv = (OUT_MODE == 2) ? 0.f : bias[col];
#pragma unroll
      for (int r2 = 0; r2 < 4; ++r2) {
        const int row = row0 + m * 16 + r2;
        float v = acc[m][n][r2] + bv;
        if (GELU_ACT) v = 0.5f * v * (1.0f + erff(v * 0.70710678118f));
        size_t idx = (size_t)row * N + col;
        if (OUT_MODE == 0) Cb[idx] = f2b(v);
        else if (OUT_MODE == 1) Cf[idx] += v;
        else Cf[idx] = v;
      }
    }
  }
}

// ---------------- 256^2 8-phase counted-vmcnt GEMM (LM head) ----------------
// C[M,N] fp32 = A[M,K]bf16 @ Bt[N,K]^T bf16.  512 thr = 8 waves (2M x 4N).
// Epilogue: LDS-staged (two 128-row chunks) fully-coalesced dwordx4 stores.
__global__ __launch_bounds__(512, 2) void gemm256_lm(
    const u16* __restrict__ A, const u16* __restrict__ Bt,
    float* __restrict__ C, int M, int N, int K) {
  extern __shared__ __align__(16) u16 smem[];   // 128 KiB
  const int tid = threadIdx.x, wid = tid >> 6, lane = tid & 63;
  const int wm = wid >> 2, wn = wid & 3;
  const int fr = lane & 15, hi = lane >> 4;
  const int T = K / 64;
  const int nwg = gridDim.x, id = blockIdx.x;
  const int q = nwg >> 3, r = nwg & 7;
  const int xcd = id & 7, i0 = id >> 3;
  const int swz = (xcd < r ? xcd * (q + 1) : r * (q + 1) + (xcd - r) * q) + i0;
  const int gm = M / 256;
  const int bm = swz % gm, bn = swz / gm;
  const int rowA0 = bm * 256, rowB0 = bn * 256;
  const int rowoff = wid * 8 + (lane >> 3);
  const int gsw = ((lane & 7) ^ (lane >> 3)) * 8;   // pre-swizzled source group
  auto stA = [&](int qq, int tt, int bb) {
    g2l16(A + (size_t)(rowA0 + qq * 64 + rowoff) * K + tt * 64 + gsw,
          smem + bb * 16384 + qq * 4096 + wid * 512);
  };
  auto stB = [&](int qq, int tt, int bb) {
    g2l16(Bt + (size_t)(rowB0 + qq * 64 + rowoff) * K + tt * 64 + gsw,
          smem + 32768 + bb * 16384 + qq * 4096 + wid * 512);
  };
  f32x4 acc[8][4] = {};
  // prologue: tile0 fully + A-even of tile1; leave the last 2 in flight
  stA(0, 0, 0); stA(2, 0, 0);
  stB(0, 0, 0); stB(1, 0, 0); stB(2, 0, 0); stB(3, 0, 0);
  stA(1, 0, 0); stA(3, 0, 0);
  if (T > 1) {
    stA(0, 1, 1); stA(2, 1, 1);
    asm volatile("s_waitcnt vmcnt(2)" ::: "memory");
  } else {
    asm volatile("s_waitcnt vmcnt(0)" ::: "memory");
  }
  __builtin_amdgcn_s_barrier();
  for (int t = 0; t < T; ++t) {
    const int cur = t & 1, nxt = cur ^ 1;
#pragma unroll
    for (int p = 0; p < 4; ++p) {
      short8v a[4][2], b[2][2];
#pragma unroll
      for (int m = 0; m < 4; ++m)
#pragma unroll
        for (int ks = 0; ks < 2; ++ks) {
          const int row = wm * 128 + (p >> 1) * 64 + m * 16 + fr;
          const int g = (ks * 4 + hi) ^ (fr & 7);
          a[m][ks] = *(const short8v*)&smem[cur * 16384 + row * 64 + g * 8];
        }
#pragma unroll
      for (int n = 0; n < 2; ++n)
#pragma unroll
        for (int ks = 0; ks < 2; ++ks) {
          const int row = wn * 64 + (p & 1) * 32 + n * 16 + fr;
          const int g = (ks * 4 + hi) ^ (fr & 7);
          b[n][ks] = *(const short8v*)&smem[32768 + cur * 16384 + row * 64 + g * 8];
        }
      if (p == 0 && t + 1 < T) { stB(0, t + 1, nxt); stB(1, t + 1, nxt); }
      if (p == 1 && t + 1 < T) { stB(2, t + 1, nxt); stB(3, t + 1, nxt); }
      if (p == 2 && t + 1 < T) { stA(1, t + 1, nxt); stA(3, t + 1, nxt); }
      if (p == 3 && t + 2 < T) { stA(0, t + 2, cur); stA(2, t + 2, cur); }
      __builtin_amdgcn_s_barrier();
      asm volatile("s_waitcnt lgkmcnt(0)" ::: "memory");
      __builtin_amdgcn_sched_barrier(0);
      __builtin_amdgcn_s_setprio(1);
#pragma unroll
      for (int ks = 0; ks < 2; ++ks)
#pragma unroll
        for (int m = 0; m < 4; ++m)
#pragma unroll
          for (int n = 0; n < 2; ++n)
            acc[(p >> 1) * 4 + m][(p & 1) * 2 + n] =
                __builtin_amdgcn_mfma_f32_16x16x32_bf16(
                    a[m][ks], b[n][ks],
                    acc[(p >> 1) * 4 + m][(p & 1) * 2 + n], 0, 0, 0);
      __builtin_amdgcn_s_setprio(0);
      if (p == 3) {
        if (t + 1 < T) {   // boundary: tile t+1 data must be resident
          if (t + 2 < T) asm volatile("s_waitcnt vmcnt(2)" ::: "memory");
          else           asm volatile("s_waitcnt vmcnt(0)" ::: "memory");
          __builtin_amdgcn_s_barrier();
        }
      } else {
        __builtin_amdgcn_s_barrier();
      }
    }
  }
  // ---- LDS-staged coalesced epilogue: 2 chunks of 128 rows x 256 cols f32 ----
  float* lf = (float*)smem;
#pragma unroll
  for (int c = 0; c < 2; ++c) {
    __syncthreads();   // K-loop LDS reads (c=0) / chunk c-1 reads (c=1) done
    if (wm == c) {
#pragma unroll
      for (int m = 0; m < 8; ++m)
#pragma unroll
        for (int n = 0; n < 4; ++n)
#pragma unroll
          for (int rr = 0; rr < 4; ++rr)
            lf[(m * 16 + hi * 4 + rr) * 256 + wn * 64 + n * 16 + fr] =
                acc[m][n][rr];
    }
    __syncthreads();
#pragma unroll
    for (int i = 0; i < 16; ++i) {
      const int f = i * 2048 + tid * 4;
      const int rw = f >> 8, cl = f & 255;
      f32x4 v = *(const f32x4*)&lf[f];
      *(f32x4*)&C[(size_t)(rowA0 + c * 128 + rw) * N + rowB0 + cl] = v;
    }
  }
}

// ---------------- flash-style MFMA attention ----------------
__global__ __launch_bounds__(256) void attn_mfma(
    const u16* __restrict__ qkv, u16* __restrict__ ctx) {
  __shared__ __align__(16) u16 smem[18432];
  u16 (*Qs)[72] = (u16(*)[72])smem;             // [128][72]
  u16 (*Ks)[72] = (u16(*)[72])(smem + 9216);    // [64][72]
  u16 (*Vs)[72] = (u16(*)[72])(smem + 13824);   // [64][72]  V^T: [d][k]
  const int qt = blockIdx.x, bh = blockIdx.y;
  const int b = bh >> 4, h = bh & 15;
  const int tid = threadIdx.x, wid = tid >> 6, lane = tid & 63;
  const int fr = lane & 15, ko = (lane >> 4) * 8;
  u16 (*Ps)[72] = (u16(*)[72])(smem + wid * 2304);  // [32][72]/wave, aliases Qs
  const size_t rb = (size_t)b * S_LEN;
  const int q0 = qt * QBLK;
  const int hq = h * 64;
#pragma unroll
  for (int i = 0; i < 4; ++i) {
    int e = tid + i * 256, r = e >> 3, c = (e & 7) * 8;
    *(short8v*)&Qs[r][c] = *(const short8v*)&qkv[(rb + q0 + r) * QKV_N + hq + c];
  }
  __syncthreads();
  short8v qf[2][2];
#pragma unroll
  for (int m = 0; m < 2; ++m)
#pragma unroll
    for (int ks = 0; ks < 2; ++ks)
      qf[m][ks] = *(const short8v*)&Qs[wid * 32 + m * 16 + fr][ks * 32 + ko];
  f32x4 acc_o[2][4] = {};
  float mrow[2][4], lrow[2][4];
#pragma unroll
  for (int m = 0; m < 2; ++m)
#pragma unroll
    for (int r = 0; r < 4; ++r) { mrow[m][r] = -1e30f; lrow[m][r] = 0.f; }
  const int nt = 2 * qt + 2;
  for (int t = 0; t < nt; ++t) {
    const int k0 = t * KVBLK;
    __syncthreads();
#pragma unroll
    for (int i = 0; i < 2; ++i) {
      int e = tid + i * 256, r = e >> 3, c = (e & 7) * 8;
      *(short8v*)&Ks[r][c] =
          *(const short8v*)&qkv[(rb + k0 + r) * QKV_N + D_MODEL + hq + c];
      short8v vv = *(const short8v*)&qkv[(rb + k0 + r) * QKV_N + 2 * D_MODEL + hq + c];
#pragma unroll
      for (int j = 0; j < 8; ++j) Vs[c + j][r] = (u16)vv[j];
    }
    __syncthreads();
    f32x4 s[2][4] = {};
    __builtin_amdgcn_s_setprio(1);
#pragma unroll
    for (int n = 0; n < 4; ++n)
#pragma unroll
      for (int ks = 0; ks < 2; ++ks) {
        short8v kf = *(const short8v*)&Ks[n * 16 + fr][ks * 32 + ko];
#pragma unroll
        for (int m = 0; m < 2; ++m)
          s[m][n] = __builtin_amdgcn_mfma_f32_16x16x32_bf16(qf[m][ks], kf, s[m][n], 0, 0, 0);
      }
    __builtin_amdgcn_s_setprio(0);
#pragma unroll
    for (int m = 0; m < 2; ++m) {
      const int rbase = q0 + wid * 32 + m * 16 + (lane >> 4) * 4;
#pragma unroll
      for (int r = 0; r < 4; ++r) {
        const int row_g = rbase + r;
        float vmax = -1e30f;
#pragma unroll
        for (int n = 0; n < 4; ++n) {
          float v = s[m][n][r] * 0.125f;
          if (k0 + n * 16 + fr > row_g) v = -1e30f;
          s[m][n][r] = v;
          vmax = fmaxf(vmax, v);
        }
#pragma unroll
        for (int off = 1; off < 16; off <<= 1) vmax = fmaxf(vmax, __shfl_xor(vmax, off, 64));
        const float mnew = fmaxf(mrow[m][r], vmax);
        const float sc = expf(mrow[m][r] - mnew);
        mrow[m][r] = mnew;
        float ssum = 0.f;
#pragma unroll
        for (int n = 0; n < 4; ++n) {
          float p = expf(s[m][n][r] - mnew);
          s[m][n][r] = p;
          ssum += p;
        }
#pragma unroll
        for (int off = 1; off < 16; off <<= 1) ssum += __shfl_xor(ssum, off, 64);
        lrow[m][r] = lrow[m][r] * sc + ssum;
#pragma unroll
        for (int n = 0; n < 4; ++n) {
          acc_o[m][n][r] *= sc;
          Ps[m * 16 + (lane >> 4) * 4 + r][n * 16 + fr] = f2b(s[m][n][r]);
        }
      }
    }
    __builtin_amdgcn_s_setprio(1);
#pragma unroll
    for (int ks = 0; ks < 2; ++ks) {
      short8v pf[2];
#pragma unroll
      for (int m = 0; m < 2; ++m) pf[m] = *(const short8v*)&Ps[m * 16 + fr][ks * 32 + ko];
#pragma unroll
      for (int n = 0; n < 4; ++n) {
        short8v vf = *(const short8v*)&Vs[n * 16 + fr][ks * 32 + ko];
#pragma unroll
        for (int m = 0; m < 2; ++m)
          acc_o[m][n] = __builtin_amdgcn_mfma_f32_16x16x32_bf16(pf[m], vf, acc_o[m][n], 0, 0, 0);
      }
    }
    __builtin_amdgcn_s_setprio(0);
  }
#pragma unroll
  for (int m = 0; m < 2; ++m)
#pragma unroll
    for (int r = 0; r < 4; ++r) {
      const int row_g = q0 + wid * 32 + m * 16 + (lane >> 4) * 4 + r;
      const float inv = 1.0f / lrow[m][r];
#pragma unroll
      for (int n = 0; n < 4; ++n)
        ctx[(rb + row_g) * D_MODEL + hq + n * 16 + fr] = f2b(acc_o[m][n][r] * inv);
    }
}

// ---------------- launch ----------------
extern "C" void kernel_launch(void* const* d_in, const int* in_sizes, int n_in,
                              void* d_out, int out_size, void* d_ws, size_t ws_size,
                              hipStream_t stream) {
  const int* x = (const int*)d_in[0];
  const float* tok_emb = (const float*)d_in[1];
  const float* wq = (const float*)d_in[2];
  const float* bq = (const float*)d_in[3];
  const float* wk = (const float*)d_in[4];
  const float* bk = (const float*)d_in[5];
  const float* wv = (const float*)d_in[6];
  const float* bv = (const float*)d_in[7];
  const float* wo = (const float*)d_in[8];
  const float* bo = (const float*)d_in[9];
  const float* ln1_g = (const float*)d_in[10];
  const float* ln1_b = (const float*)d_in[11];
  const float* w1 = (const float*)d_in[12];
  const float* b1 = (const float*)d_in[13];
  const float* w2 = (const float*)d_in[14];
  const float* b2 = (const float*)d_in[15];
  const float* ln2_g = (const float*)d_in[16];
  const float* ln2_b = (const float*)d_in[17];
  const float* lnf_g = (const float*)d_in[18];
  const float* lnf_b = (const float*)d_in[19];
  const float* lm_w = (const float*)d_in[20];

  char* w = (char*)d_ws;
  float* h    = (float*)(w);                      // 8 MB   fp32 residual
  u16*  hn    = (u16*)(w + (8ll << 20));          // 4 MB   bf16 LN out
  u16*  qkvb  = (u16*)(w + (12ll << 20));         // 12 MB  bf16 packed qkv
  u16*  cbuf  = (u16*)(w + (24ll << 20));         // 4 MB   bf16 attn ctx
  u16*  ff    = qkvb;                             // 16 MB  alias qkv+cbuf
  u16*  wqkvT = (u16*)(w + (28ll << 20));         // 36 MB  [L][3072][1024]
  u16*  woT   = (u16*)(w + (64ll << 20));         // 12 MB  [L][1024][1024]
  u16*  w1T   = (u16*)(w + (76ll << 20));         // 48 MB  [L][4096][1024]
  u16*  w2T   = (u16*)(w + (124ll << 20));        // 48 MB  [L][1024][4096]
  u16*  lmT   = (u16*)(w + (172ll << 20));        // 62.5MB [32000][1024]
  float* bqkv = (float*)(w + (235ll << 20));      // 72 KB  [L][3072]

  const size_t DD = (size_t)D_MODEL * D_MODEL;
  const size_t DDF = (size_t)D_MODEL * DF_DIM;
  const long QS = (long)QKV_N * D_MODEL;
  transpose_cvt<<<dim3(32, 16, L_NUM), 256, 0, stream>>>(wq, wqkvT, D_MODEL, D_MODEL, QS);
  transpose_cvt<<<dim3(32, 16, L_NUM), 256, 0, stream>>>(wk, wqkvT + DD, D_MODEL, D_MODEL, QS);
  transpose_cvt<<<dim3(32, 16, L_NUM), 256, 0, stream>>>(wv, wqkvT + 2 * DD, D_MODEL, D_MODEL, QS);
  transpose_cvt<<<dim3(32, 16, L_NUM), 256, 0, stream>>>(wo, woT, D_MODEL, D_MODEL, (long)DD);
  transpose_cvt<<<dim3(128, 16, L_NUM), 256, 0, stream>>>(w1, w1T, D_MODEL, DF_DIM, (long)DDF);
  transpose_cvt<<<dim3(32, 64, L_NUM), 256, 0, stream>>>(w2, w2T, DF_DIM, D_MODEL, (long)DDF);
  transpose_cvt<<<dim3(V_SIZE / 32, 16, 1), 256, 0, stream>>>(lm_w, lmT, D_MODEL, V_SIZE, 0);
  pack_qkv_bias<<<L_NUM * QKV_N / 256, 256, 0, stream>>>(bq, bk, bv, bqkv);

  embed_kernel<<<ROWS, 256, 0, stream>>>(x, tok_emb, h);

  const int nQKV = (ROWS / 128) * (QKV_N / 128);   // 384
  const int nPRJ = (ROWS / 64) * (D_MODEL / 128);  // 256
  const int nFF1 = (ROWS / 128) * (DF_DIM / 128);  // 512
  const int nFF2 = (ROWS / 64) * (D_MODEL / 128);  // 256
  for (int l = 0; l < L_NUM; ++l) {
    layernorm_kernel<<<ROWS / 4, 256, 0, stream>>>(h, ln1_g + l * D_MODEL, ln1_b + l * D_MODEL, hn);
    gemm_bf16<128, 0, false><<<nQKV, 256, 0, stream>>>(
        hn, wqkvT + (size_t)l * QS, bqkv + l * QKV_N, nullptr, qkvb,
        ROWS, QKV_N, D_MODEL);
    attn_mfma<<<dim3(S_LEN / QBLK, B_SZ * H_NUM), 256, 0, stream>>>(qkvb, cbuf);
    gemm_bf16<64, 1, false><<<nPRJ, 256, 0, stream>>>(
        cbuf, woT + l * DD, bo + l * D_MODEL, h, nullptr, ROWS, D_MODEL, D_MODEL);
    layernorm_kernel<<<ROWS / 4, 256, 0, stream>>>(h, ln2_g + l * D_MODEL, ln2_b + l * D_MODEL, hn);
    gemm_bf16<128, 0, true><<<nFF1, 256, 0, stream>>>(
        hn, w1T + l * DDF, b1 + l * DF_DIM, nullptr, ff, ROWS, DF_DIM, D_MODEL);
    gemm_bf16<64, 1, false><<<nFF2, 256, 0, stream>>>(
        ff, w2T + l * DDF, b2 + l * D_MODEL, h, nullptr, ROWS, D_MODEL, DF_DIM);
  }
  layernorm_kernel<<<ROWS / 4, 256, 0, stream>>>(h, lnf_g, lnf_b, hn);

  hipFuncSetAttribute((const void*)gemm256_lm,
                      hipFuncAttributeMaxDynamicSharedMemorySize, 131072);
  const int nLM = (ROWS / 256) * (V_SIZE / 256);   // 8 * 125 = 1000
  gemm256_lm<<<nLM, 512, 131072, stream>>>(
      hn, lmT, (float*)d_out, ROWS, V_SIZE, D_MODEL);
}

// Round 7
// 1645.214 us; speedup vs baseline: 7.0597x; 1.0289x over previous
//
#include <hip/hip_runtime.h>
#include <hip/hip_bf16.h>
#include <math.h>

// GPT forward. V=32000 L=6 H=16 D=1024 S=512 B=4, DK=64, DF=4096.
// Round 6: LM-head snake-quadrant register reuse (LDS traffic 48->28 reads
// per K-tile); attention QBLK=64 for load balance (512 blocks).
#define V_SIZE 32000
#define L_NUM 6
#define H_NUM 16
#define D_MODEL 1024
#define S_LEN 512
#define B_SZ 4
#define DF_DIM 4096
#define ROWS (B_SZ * S_LEN)   // 2048
#define QKV_N (3 * D_MODEL)   // 3072
#define KVBLK 64

typedef unsigned short u16;
typedef __attribute__((ext_vector_type(8))) short short8v;   // 8 bf16
typedef __attribute__((ext_vector_type(4))) float f32x4;

__device__ __forceinline__ float b2f(u16 b) {
  union { float f; unsigned u; } c; c.u = ((unsigned)b) << 16; return c.f;
}
__device__ __forceinline__ u16 f2b(float f) {
  __hip_bfloat16 h = __float2bfloat16(f);
  union { __hip_bfloat16 h; u16 u; } c; c.h = h; return c.u;
}
__device__ __forceinline__ void g2l16(const void* g, void* l) {
  __builtin_amdgcn_global_load_lds(
      (const __attribute__((address_space(1))) void*)g,
      (__attribute__((address_space(3))) void*)l, 16, 0, 0);
}

// ---------------- embedding + sinusoidal PE (fp32 out) ----------------
__global__ __launch_bounds__(256) void embed_kernel(
    const int* __restrict__ x, const float* __restrict__ tok_emb,
    float* __restrict__ h) {
  int row = blockIdx.x;
  int s = row % S_LEN;
  int tok = x[row];
  const float* te = tok_emb + (size_t)tok * D_MODEL;
  float* hr = h + (size_t)row * D_MODEL;
  float pos = (float)s;
  const float c = 9.210340371976184f / (float)D_MODEL;  // ln(10000)/D
#pragma unroll
  for (int i = 0; i < D_MODEL / 256; ++i) {
    int d = threadIdx.x + i * 256;
    float freq = expf(-(float)(d & ~1) * c);
    float ang = pos * freq;
    float pe = (d & 1) ? cosf(ang) : sinf(ang);
    hr[d] = te[d] + pe;
  }
}

// ---------------- layernorm: wave per row, float4 loads, bf16 out ----------------
__global__ __launch_bounds__(256) void layernorm_kernel(
    const float* __restrict__ in, const float* __restrict__ g,
    const float* __restrict__ b, u16* __restrict__ out) {
  const int row = blockIdx.x * 4 + (threadIdx.x >> 6);
  const int lane = threadIdx.x & 63;
  const float4* xr = (const float4*)(in + (size_t)row * D_MODEL);
  float4 v[4];
  float s1 = 0.f, s2 = 0.f;
#pragma unroll
  for (int i = 0; i < 4; ++i) {
    float4 t = xr[lane + i * 64];
    v[i] = t;
    s1 += t.x + t.y + t.z + t.w;
    s2 += t.x * t.x + t.y * t.y + t.z * t.z + t.w * t.w;
  }
#pragma unroll
  for (int off = 32; off; off >>= 1) {
    s1 += __shfl_xor(s1, off, 64);
    s2 += __shfl_xor(s2, off, 64);
  }
  const float mu = s1 * (1.0f / D_MODEL);
  const float var = s2 * (1.0f / D_MODEL) - mu * mu;
  const float rstd = rsqrtf(var + 1e-5f);
  u16* orow = out + (size_t)row * D_MODEL;
#pragma unroll
  for (int i = 0; i < 4; ++i) {
    const int d = (lane + i * 64) * 4;
    const float4 gv = *(const float4*)&g[d];
    const float4 bv = *(const float4*)&b[d];
    u16 o0 = f2b((v[i].x - mu) * rstd * gv.x + bv.x);
    u16 o1 = f2b((v[i].y - mu) * rstd * gv.y + bv.y);
    u16 o2 = f2b((v[i].z - mu) * rstd * gv.z + bv.z);
    u16 o3 = f2b((v[i].w - mu) * rstd * gv.w + bv.w);
    uint2 pk;
    pk.x = (unsigned)o0 | ((unsigned)o1 << 16);
    pk.y = (unsigned)o2 | ((unsigned)o3 << 16);
    *(uint2*)&orow[d] = pk;
  }
}

// ---------------- fp32 [K][N] -> bf16 [N][K] transpose (batched over z) ----------------
__global__ __launch_bounds__(256) void transpose_cvt(
    const float* __restrict__ W, u16* __restrict__ Wt, int K, int N,
    long out_stride) {
  __shared__ float t[64][33];
  const float* Wl = W + (size_t)blockIdx.z * K * N;
  u16* Wtl = Wt + (size_t)blockIdx.z * out_stride;
  const int n0 = blockIdx.x * 32, k0 = blockIdx.y * 64;
  const int tx = threadIdx.x & 31, ty = threadIdx.x >> 5;   // ty 0..7
#pragma unroll
  for (int i = 0; i < 64; i += 8)
    t[ty + i][tx] = Wl[(size_t)(k0 + ty + i) * N + n0 + tx];
  __syncthreads();
#pragma unroll
  for (int j = 0; j < 32; j += 8) {
    const int n = ty + j;
    u16 lo = f2b(t[2 * tx][n]);
    u16 hi = f2b(t[2 * tx + 1][n]);
    *(unsigned*)&Wtl[(size_t)(n0 + n) * K + k0 + 2 * tx] =
        (unsigned)lo | ((unsigned)hi << 16);
  }
}

// ---------------- pack bq|bk|bv -> [L][3072] ----------------
__global__ __launch_bounds__(256) void pack_qkv_bias(
    const float* __restrict__ bq, const float* __restrict__ bk,
    const float* __restrict__ bv, float* __restrict__ out) {
  int i = blockIdx.x * 256 + threadIdx.x;   // 0 .. L*3072-1
  int l = i / QKV_N, j = i % QKV_N;
  float v = (j < D_MODEL) ? bq[l * D_MODEL + j]
          : (j < 2 * D_MODEL) ? bk[l * D_MODEL + j - D_MODEL]
          : bv[l * D_MODEL + j - 2 * D_MODEL];
  out[i] = v;
}

// ---------------- bf16 MFMA GEMM (2-phase prefetch): C = A @ Bt^T ----------------
template <int TM, int OUT_MODE, bool GELU_ACT>
__global__ __launch_bounds__(256) void gemm_bf16(
    const u16* __restrict__ A, const u16* __restrict__ Bt,
    const float* __restrict__ bias, float* __restrict__ Cf,
    u16* __restrict__ Cb, int M, int N, int K) {
  constexpr int MF = TM / 32;
  constexpr int ALOADS = TM / 64;
  __shared__ __align__(16) u16 As[2][TM * 32];
  __shared__ __align__(16) u16 Bs[2][128 * 32];
  const int tid = threadIdx.x;
  const int wid = tid >> 6;
  const int lane = tid & 63;
  const int wr = wid >> 1, wc = wid & 1;
  const int nwg = gridDim.x;
  const int id = blockIdx.x;
  const int q = nwg >> 3, r = nwg & 7;
  const int xcd = id & 7, i0 = id >> 3;
  const int swz = (xcd < r ? xcd * (q + 1) : r * (q + 1) + (xcd - r) * q) + i0;
  const int gm = M / TM;
  const int bm = swz % gm, bn = swz / gm;
  const u16* Ag = A + (size_t)(bm * TM + wid * (TM / 4) + (lane >> 2)) * K + (lane & 3) * 8;
  const u16* Bg = Bt + (size_t)(bn * 128 + wid * 32 + (lane >> 2)) * K + (lane & 3) * 8;
  auto stage = [&](int buf, int k0) {
#pragma unroll
    for (int i = 0; i < ALOADS; ++i)
      g2l16(Ag + k0 + (size_t)(16 * i) * K, As[buf] + wid * (TM / 4) * 32 + 512 * i);
    g2l16(Bg + k0, Bs[buf] + wid * 1024);
    g2l16(Bg + k0 + (size_t)16 * K, Bs[buf] + wid * 1024 + 512);
  };
  f32x4 acc[MF][4] = {};
  const int fr = lane & 15;
  const int ko = (lane >> 4) * 8;
  stage(0, 0);
  __syncthreads();
  for (int k0 = 0; k0 < K; k0 += 32) {
    const int cur = (k0 >> 5) & 1;
    if (k0 + 32 < K) stage(cur ^ 1, k0 + 32);
    short8v a[MF], b[4];
#pragma unroll
    for (int m = 0; m < MF; ++m)
      a[m] = *(const short8v*)&As[cur][(wr * (TM / 2) + m * 16 + fr) * 32 + ko];
#pragma unroll
    for (int n = 0; n < 4; ++n)
      b[n] = *(const short8v*)&Bs[cur][(wc * 64 + n * 16 + fr) * 32 + ko];
#pragma unroll
    for (int m = 0; m < MF; ++m)
#pragma unroll
      for (int n = 0; n < 4; ++n)
        acc[m][n] = __builtin_amdgcn_mfma_f32_16x16x32_bf16(a[m], b[n], acc[m][n], 0, 0, 0);
    __syncthreads();   // drains next-tile stage (vmcnt0) + barrier
  }
  const int row0 = bm * TM + wr * (TM / 2) + (lane >> 4) * 4;
  const int col0 = bn * 128 + wc * 64 + fr;
#pragma unroll
  for (int m = 0; m < MF; ++m) {
#pragma unroll
    for (int n = 0; n < 4; ++n) {
      const int col = col0 + n * 16;
      float bv = (OUT_MODE == 2) ? 0.f : bias[col];
#pragma unroll
      for (int r2 = 0; r2 < 4; ++r2) {
        const int row = row0 + m * 16 + r2;
        float v = acc[m][n][r2] + bv;
        if (GELU_ACT) v = 0.5f * v * (1.0f + erff(v * 0.70710678118f));
        size_t idx = (size_t)row * N + col;
        if (OUT_MODE == 0) Cb[idx] = f2b(v);
        else if (OUT_MODE == 1) Cf[idx] += v;
        else Cf[idx] = v;
      }
    }
  }
}

// ---------------- 256^2 8-phase counted-vmcnt GEMM (LM head) ----------------
// Snake-quadrant order with register-resident fragments:
//   p0: LDA(h0)+LDB(h0) -> Q(0,0);  p1: LDB(h1) -> Q(0,1) [A held];
//   p2: LDA(h1) -> Q(1,1) [B held]; p3: LDB(h0) -> Q(1,0) [A held].
// 28 ds_read_b128 per K-tile instead of 48. Stage/vmcnt skeleton unchanged.
#define LDA_H(H)                                                            \
  _Pragma("unroll") for (int m = 0; m < 4; ++m)                             \
  _Pragma("unroll") for (int ks = 0; ks < 2; ++ks) {                        \
    const int row_ = wm * 128 + (H)*64 + m * 16 + fr;                       \
    const int g_ = (ks * 4 + hi) ^ (fr & 7);                                \
    a[m][ks] = *(const short8v*)&smem[cur * 16384 + row_ * 64 + g_ * 8];    \
  }
#define LDB_H(H)                                                            \
  _Pragma("unroll") for (int n = 0; n < 2; ++n)                             \
  _Pragma("unroll") for (int ks = 0; ks < 2; ++ks) {                        \
    const int row_ = wn * 64 + (H)*32 + n * 16 + fr;                        \
    const int g_ = (ks * 4 + hi) ^ (fr & 7);                                \
    b[n][ks] = *(const short8v*)&smem[32768 + cur * 16384 + row_ * 64 + g_ * 8]; \
  }
#define MFMA_CLUSTER(QA, QB)                                                \
  __builtin_amdgcn_s_barrier();                                             \
  asm volatile("s_waitcnt lgkmcnt(0)" ::: "memory");                        \
  __builtin_amdgcn_sched_barrier(0);                                        \
  __builtin_amdgcn_s_setprio(1);                                            \
  _Pragma("unroll") for (int ks = 0; ks < 2; ++ks)                          \
  _Pragma("unroll") for (int m = 0; m < 4; ++m)                             \
  _Pragma("unroll") for (int n = 0; n < 2; ++n)                             \
    acc[(QA)*4 + m][(QB)*2 + n] = __builtin_amdgcn_mfma_f32_16x16x32_bf16(  \
        a[m][ks], b[n][ks], acc[(QA)*4 + m][(QB)*2 + n], 0, 0, 0);          \
  __builtin_amdgcn_s_setprio(0);

__global__ __launch_bounds__(512, 2) void gemm256_lm(
    const u16* __restrict__ A, const u16* __restrict__ Bt,
    float* __restrict__ C, int M, int N, int K) {
  extern __shared__ __align__(16) u16 smem[];   // 128 KiB
  const int tid = threadIdx.x, wid = tid >> 6, lane = tid & 63;
  const int wm = wid >> 2, wn = wid & 3;
  const int fr = lane & 15, hi = lane >> 4;
  const int T = K / 64;
  const int nwg = gridDim.x, id = blockIdx.x;
  const int q = nwg >> 3, r = nwg & 7;
  const int xcd = id & 7, i0 = id >> 3;
  const int swz = (xcd < r ? xcd * (q + 1) : r * (q + 1) + (xcd - r) * q) + i0;
  const int gm = M / 256;
  const int bm = swz % gm, bn = swz / gm;
  const int rowA0 = bm * 256, rowB0 = bn * 256;
  const int rowoff = wid * 8 + (lane >> 3);
  const int gsw = ((lane & 7) ^ (lane >> 3)) * 8;   // pre-swizzled source group
  auto stA = [&](int qq, int tt, int bb) {
    g2l16(A + (size_t)(rowA0 + qq * 64 + rowoff) * K + tt * 64 + gsw,
          smem + bb * 16384 + qq * 4096 + wid * 512);
  };
  auto stB = [&](int qq, int tt, int bb) {
    g2l16(Bt + (size_t)(rowB0 + qq * 64 + rowoff) * K + tt * 64 + gsw,
          smem + 32768 + bb * 16384 + qq * 4096 + wid * 512);
  };
  f32x4 acc[8][4] = {};
  // prologue: tile0 fully + A-even of tile1; leave the last 2 in flight
  stA(0, 0, 0); stA(2, 0, 0);
  stB(0, 0, 0); stB(1, 0, 0); stB(2, 0, 0); stB(3, 0, 0);
  stA(1, 0, 0); stA(3, 0, 0);
  if (T > 1) {
    stA(0, 1, 1); stA(2, 1, 1);
    asm volatile("s_waitcnt vmcnt(2)" ::: "memory");
  } else {
    asm volatile("s_waitcnt vmcnt(0)" ::: "memory");
  }
  __builtin_amdgcn_s_barrier();
  for (int t = 0; t < T; ++t) {
    const int cur = t & 1, nxt = cur ^ 1;
    short8v a[4][2], b[2][2];
    // phase 0: Q(0,0)
    LDA_H(0); LDB_H(0);
    if (t + 1 < T) { stB(0, t + 1, nxt); stB(1, t + 1, nxt); }
    MFMA_CLUSTER(0, 0);
    __builtin_amdgcn_s_barrier();
    // phase 1: Q(0,1) -- A half 0 held in regs
    LDB_H(1);
    if (t + 1 < T) { stB(2, t + 1, nxt); stB(3, t + 1, nxt); }
    MFMA_CLUSTER(0, 1);
    __builtin_amdgcn_s_barrier();
    // phase 2: Q(1,1) -- B half 1 held in regs
    LDA_H(1);
    if (t + 1 < T) { stA(1, t + 1, nxt); stA(3, t + 1, nxt); }
    MFMA_CLUSTER(1, 1);
    __builtin_amdgcn_s_barrier();
    // phase 3: Q(1,0) -- A half 1 held, B half 0 re-read
    LDB_H(0);
    if (t + 2 < T) { stA(0, t + 2, cur); stA(2, t + 2, cur); }
    MFMA_CLUSTER(1, 0);
    if (t + 1 < T) {   // boundary: tile t+1 data must be resident
      if (t + 2 < T) asm volatile("s_waitcnt vmcnt(2)" ::: "memory");
      else           asm volatile("s_waitcnt vmcnt(0)" ::: "memory");
      __builtin_amdgcn_s_barrier();
    }
  }
  // ---- LDS-staged coalesced epilogue: 2 chunks of 128 rows x 256 cols f32 ----
  float* lf = (float*)smem;
#pragma unroll
  for (int c = 0; c < 2; ++c) {
    __syncthreads();   // K-loop LDS reads (c=0) / chunk c-1 reads (c=1) done
    if (wm == c) {
#pragma unroll
      for (int m = 0; m < 8; ++m)
#pragma unroll
        for (int n = 0; n < 4; ++n)
#pragma unroll
          for (int rr = 0; rr < 4; ++rr)
            lf[(m * 16 + hi * 4 + rr) * 256 + wn * 64 + n * 16 + fr] =
                acc[m][n][rr];
    }
    __syncthreads();
#pragma unroll
    for (int i = 0; i < 16; ++i) {
      const int f = i * 2048 + tid * 4;
      const int rw = f >> 8, cl = f & 255;
      f32x4 v = *(const f32x4*)&lf[f];
      *(f32x4*)&C[(size_t)(rowA0 + c * 128 + rw) * N + rowB0 + cl] = v;
    }
  }
}

// ---------------- flash-style MFMA attention, QBLK=64 ----------------
// grid (S/64=8, B*H=64), 256 thr = 4 waves; wave owns 16 q-rows.
__global__ __launch_bounds__(256) void attn_mfma(
    const u16* __restrict__ qkv, u16* __restrict__ ctx) {
  __shared__ __align__(16) u16 smem[3 * 64 * 72];   // 27 KB
  u16 (*Qs)[72] = (u16(*)[72])smem;             // [64][72]
  u16 (*Ks)[72] = (u16(*)[72])(smem + 4608);    // [64][72]
  u16 (*Vs)[72] = (u16(*)[72])(smem + 9216);    // [64][72]  V^T: [d][k]
  const int qt = blockIdx.x, bh = blockIdx.y;
  const int b = bh >> 4, h = bh & 15;
  const int tid = threadIdx.x, wid = tid >> 6, lane = tid & 63;
  const int fr = lane & 15, ko = (lane >> 4) * 8;
  u16 (*Ps)[72] = (u16(*)[72])(smem + wid * 1152);  // [16][72]/wave, aliases Qs
  const size_t rb = (size_t)b * S_LEN;
  const int q0 = qt * 64;
  const int hq = h * 64;
  // stage Q tile (64 rows x 64 cols)
#pragma unroll
  for (int i = 0; i < 2; ++i) {
    int e = tid + i * 256, r = e >> 3, c = (e & 7) * 8;
    *(short8v*)&Qs[r][c] = *(const short8v*)&qkv[(rb + q0 + r) * QKV_N + hq + c];
  }
  __syncthreads();
  short8v qf[2];
#pragma unroll
  for (int ks = 0; ks < 2; ++ks)
    qf[ks] = *(const short8v*)&Qs[wid * 16 + fr][ks * 32 + ko];
  f32x4 acc_o[4] = {};
  float mrow[4], lrow[4];
#pragma unroll
  for (int r = 0; r < 4; ++r) { mrow[r] = -1e30f; lrow[r] = 0.f; }
  const int nt = qt + 1;
  for (int t = 0; t < nt; ++t) {
    const int k0 = t * KVBLK;
    __syncthreads();   // Ks/Vs reads (prev iter) + Qs->Ps alias done
#pragma unroll
    for (int i = 0; i < 2; ++i) {
      int e = tid + i * 256, r = e >> 3, c = (e & 7) * 8;
      *(short8v*)&Ks[r][c] =
          *(const short8v*)&qkv[(rb + k0 + r) * QKV_N + D_MODEL + hq + c];
      short8v vv = *(const short8v*)&qkv[(rb + k0 + r) * QKV_N + 2 * D_MODEL + hq + c];
#pragma unroll
      for (int j = 0; j < 8; ++j) Vs[c + j][r] = (u16)vv[j];
    }
    __syncthreads();
    // S = Q K^T
    f32x4 s[4] = {};
    __builtin_amdgcn_s_setprio(1);
#pragma unroll
    for (int n = 0; n < 4; ++n)
#pragma unroll
      for (int ks = 0; ks < 2; ++ks) {
        short8v kf = *(const short8v*)&Ks[n * 16 + fr][ks * 32 + ko];
        s[n] = __builtin_amdgcn_mfma_f32_16x16x32_bf16(qf[ks], kf, s[n], 0, 0, 0);
      }
    __builtin_amdgcn_s_setprio(0);
    // mask + online softmax
    const int rbase = q0 + wid * 16 + (lane >> 4) * 4;
#pragma unroll
    for (int r = 0; r < 4; ++r) {
      const int row_g = rbase + r;
      float vmax = -1e30f;
#pragma unroll
      for (int n = 0; n < 4; ++n) {
        float v = s[n][r] * 0.125f;
        if (k0 + n * 16 + fr > row_g) v = -1e30f;
        s[n][r] = v;
        vmax = fmaxf(vmax, v);
      }
#pragma unroll
      for (int off = 1; off < 16; off <<= 1) vmax = fmaxf(vmax, __shfl_xor(vmax, off, 64));
      const float mnew = fmaxf(mrow[r], vmax);
      const float sc = expf(mrow[r] - mnew);
      mrow[r] = mnew;
      float ssum = 0.f;
#pragma unroll
      for (int n = 0; n < 4; ++n) {
        float p = expf(s[n][r] - mnew);
        s[n][r] = p;
        ssum += p;
      }
#pragma unroll
      for (int off = 1; off < 16; off <<= 1) ssum += __shfl_xor(ssum, off, 64);
      lrow[r] = lrow[r] * sc + ssum;
#pragma unroll
      for (int n = 0; n < 4; ++n) {
        acc_o[n][r] *= sc;
        Ps[(lane >> 4) * 4 + r][n * 16 + fr] = f2b(s[n][r]);
      }
    }
    // O += P V  (wave-private Ps)
    __builtin_amdgcn_s_setprio(1);
#pragma unroll
    for (int ks = 0; ks < 2; ++ks) {
      short8v pf = *(const short8v*)&Ps[fr][ks * 32 + ko];
#pragma unroll
      for (int n = 0; n < 4; ++n) {
        short8v vf = *(const short8v*)&Vs[n * 16 + fr][ks * 32 + ko];
        acc_o[n] = __builtin_amdgcn_mfma_f32_16x16x32_bf16(pf, vf, acc_o[n], 0, 0, 0);
      }
    }
    __builtin_amdgcn_s_setprio(0);
  }
  // epilogue
#pragma unroll
  for (int r = 0; r < 4; ++r) {
    const int row_g = q0 + wid * 16 + (lane >> 4) * 4 + r;
    const float inv = 1.0f / lrow[r];
#pragma unroll
    for (int n = 0; n < 4; ++n)
      ctx[(rb + row_g) * D_MODEL + hq + n * 16 + fr] = f2b(acc_o[n][r] * inv);
  }
}

// ---------------- launch ----------------
extern "C" void kernel_launch(void* const* d_in, const int* in_sizes, int n_in,
                              void* d_out, int out_size, void* d_ws, size_t ws_size,
                              hipStream_t stream) {
  const int* x = (const int*)d_in[0];
  const float* tok_emb = (const float*)d_in[1];
  const float* wq = (const float*)d_in[2];
  const float* bq = (const float*)d_in[3];
  const float* wk = (const float*)d_in[4];
  const float* bk = (const float*)d_in[5];
  const float* wv = (const float*)d_in[6];
  const float* bv = (const float*)d_in[7];
  const float* wo = (const float*)d_in[8];
  const float* bo = (const float*)d_in[9];
  const float* ln1_g = (const float*)d_in[10];
  const float* ln1_b = (const float*)d_in[11];
  const float* w1 = (const float*)d_in[12];
  const float* b1 = (const float*)d_in[13];
  const float* w2 = (const float*)d_in[14];
  const float* b2 = (const float*)d_in[15];
  const float* ln2_g = (const float*)d_in[16];
  const float* ln2_b = (const float*)d_in[17];
  const float* lnf_g = (const float*)d_in[18];
  const float* lnf_b = (const float*)d_in[19];
  const float* lm_w = (const float*)d_in[20];

  char* w = (char*)d_ws;
  float* h    = (float*)(w);                      // 8 MB   fp32 residual
  u16*  hn    = (u16*)(w + (8ll << 20));          // 4 MB   bf16 LN out
  u16*  qkvb  = (u16*)(w + (12ll << 20));         // 12 MB  bf16 packed qkv
  u16*  cbuf  = (u16*)(w + (24ll << 20));         // 4 MB   bf16 attn ctx
  u16*  ff    = qkvb;                             // 16 MB  alias qkv+cbuf
  u16*  wqkvT = (u16*)(w + (28ll << 20));         // 36 MB  [L][3072][1024]
  u16*  woT   = (u16*)(w + (64ll << 20));         // 12 MB  [L][1024][1024]
  u16*  w1T   = (u16*)(w + (76ll << 20));         // 48 MB  [L][4096][1024]
  u16*  w2T   = (u16*)(w + (124ll << 20));        // 48 MB  [L][1024][4096]
  u16*  lmT   = (u16*)(w + (172ll << 20));        // 62.5MB [32000][1024]
  float* bqkv = (float*)(w + (235ll << 20));      // 72 KB  [L][3072]

  const size_t DD = (size_t)D_MODEL * D_MODEL;
  const size_t DDF = (size_t)D_MODEL * DF_DIM;
  const long QS = (long)QKV_N * D_MODEL;
  transpose_cvt<<<dim3(32, 16, L_NUM), 256, 0, stream>>>(wq, wqkvT, D_MODEL, D_MODEL, QS);
  transpose_cvt<<<dim3(32, 16, L_NUM), 256, 0, stream>>>(wk, wqkvT + DD, D_MODEL, D_MODEL, QS);
  transpose_cvt<<<dim3(32, 16, L_NUM), 256, 0, stream>>>(wv, wqkvT + 2 * DD, D_MODEL, D_MODEL, QS);
  transpose_cvt<<<dim3(32, 16, L_NUM), 256, 0, stream>>>(wo, woT, D_MODEL, D_MODEL, (long)DD);
  transpose_cvt<<<dim3(128, 16, L_NUM), 256, 0, stream>>>(w1, w1T, D_MODEL, DF_DIM, (long)DDF);
  transpose_cvt<<<dim3(32, 64, L_NUM), 256, 0, stream>>>(w2, w2T, DF_DIM, D_MODEL, (long)DDF);
  transpose_cvt<<<dim3(V_SIZE / 32, 16, 1), 256, 0, stream>>>(lm_w, lmT, D_MODEL, V_SIZE, 0);
  pack_qkv_bias<<<L_NUM * QKV_N / 256, 256, 0, stream>>>(bq, bk, bv, bqkv);

  embed_kernel<<<ROWS, 256, 0, stream>>>(x, tok_emb, h);

  const int nQKV = (ROWS / 128) * (QKV_N / 128);   // 384
  const int nPRJ = (ROWS / 64) * (D_MODEL / 128);  // 256
  const int nFF1 = (ROWS / 128) * (DF_DIM / 128);  // 512
  const int nFF2 = (ROWS / 64) * (D_MODEL / 128);  // 256
  for (int l = 0; l < L_NUM; ++l) {
    layernorm_kernel<<<ROWS / 4, 256, 0, stream>>>(h, ln1_g + l * D_MODEL, ln1_b + l * D_MODEL, hn);
    gemm_bf16<128, 0, false><<<nQKV, 256, 0, stream>>>(
        hn, wqkvT + (size_t)l * QS, bqkv + l * QKV_N, nullptr, qkvb,
        ROWS, QKV_N, D_MODEL);
    attn_mfma<<<dim3(S_LEN / 64, B_SZ * H_NUM), 256, 0, stream>>>(qkvb, cbuf);
    gemm_bf16<64, 1, false><<<nPRJ, 256, 0, stream>>>(
        cbuf, woT + l * DD, bo + l * D_MODEL, h, nullptr, ROWS, D_MODEL, D_MODEL);
    layernorm_kernel<<<ROWS / 4, 256, 0, stream>>>(h, ln2_g + l * D_MODEL, ln2_b + l * D_MODEL, hn);
    gemm_bf16<128, 0, true><<<nFF1, 256, 0, stream>>>(
        hn, w1T + l * DDF, b1 + l * DF_DIM, nullptr, ff, ROWS, DF_DIM, D_MODEL);
    gemm_bf16<64, 1, false><<<nFF2, 256, 0, stream>>>(
        ff, w2T + l * DDF, b2 + l * D_MODEL, h, nullptr, ROWS, D_MODEL, DF_DIM);
  }
  layernorm_kernel<<<ROWS / 4, 256, 0, stream>>>(h, lnf_g, lnf_b, hn);

  hipFuncSetAttribute((const void*)gemm256_lm,
                      hipFuncAttributeMaxDynamicSharedMemorySize, 131072);
  const int nLM = (ROWS / 256) * (V_SIZE / 256);   // 8 * 125 = 1000
  gemm256_lm<<<nLM, 512, 131072, stream>>>(
      hn, lmT, (float*)d_out, ROWS, V_SIZE, D_MODEL);
}